// Round 4
// baseline (1567.382 us; speedup 1.0000x reference)
//
#include <hip/hip_runtime.h>
#include <math.h>

constexpr int GG  = 1024;   // graphs
constexpr int NN  = 256;    // nodes layer0
constexpr int FF  = 128;    // input feat
constexpr int DD  = 256;    // hidden
constexpr int KS0 = 32, KS1 = 16, KS2 = 8;
constexpr int MAXNB = 96;   // max neighbors stored

__device__ __forceinline__ float lrelu(float x){ return x >= 0.f ? x : 0.01f*x; }

// bf16 helpers
__device__ __forceinline__ unsigned short f2bf(float f) {
  unsigned u = __float_as_uint(f);
  unsigned r = (u + 0x7FFFu + ((u >> 16) & 1u)) >> 16;
  return (unsigned short)r;
}
__device__ __forceinline__ float bf2f(unsigned short h) {
  return __uint_as_float(((unsigned)h) << 16);
}

typedef __attribute__((ext_vector_type(8)))  __bf16 bf16x8;
typedef __attribute__((ext_vector_type(16))) float  f32x16;

union U64pack { unsigned short us[4]; unsigned long long u; };
union Frag8   { unsigned short us[8]; unsigned long long u64[2]; bf16x8 v; };

// ---------------- pre-split weights into 3 bf16 planes, k-major [3][DD][K] ----------------
// Wk[((sp*DD + n)*K) + k] = split_sp(W[k*DD + n]); fragment loads become contiguous 16B.
__global__ void k_splitW(const float* __restrict__ W, unsigned short* __restrict__ out, int K) {
  int e = blockIdx.x*256 + threadIdx.x;     // e over DD*K (n-major, k-contiguous)
  if (e >= DD*K) return;
  int n = e / K, k = e - n*K;
  float x = W[(size_t)k*DD + n];
  unsigned short h1 = f2bf(x);  float r1 = x - bf2f(h1);
  unsigned short h2 = f2bf(r1); float r2 = r1 - bf2f(h2);
  unsigned short h3 = f2bf(r2);
  out[e] = h1; out[DD*K + e] = h2; out[2*DD*K + e] = h3;
}

// ---------------- merged: CSR build + norm + T0 = A @ (X*norm) via bf16 MFMA ----------------
__global__ __launch_bounds__(256) void k_spmm_mfma(
    const float* __restrict__ adj, const float* __restrict__ feat,
    float* __restrict__ norm0, int* __restrict__ cnt0, unsigned char* __restrict__ nbr0,
    float* __restrict__ T0) {
  __shared__ unsigned long long xs[3*128*9];       // 27648 B
  __shared__ float snorm[NN];

  int g = blockIdx.x;
  int t = threadIdx.x;
  int lane = t & 63, wave = t >> 6;
  int lm = lane & 31, lh = lane >> 5;

  const float* Ag = adj  + (size_t)g*NN*NN;
  const float* Xg = feat + (size_t)g*NN*FF;

  // ---- phase 0: CSR + norm for this wave's 64 rows ----
  for (int r = wave*64; r < wave*64 + 64; ++r) {
    unsigned char* nb = nbr0 + ((size_t)g*NN + r)*MAXNB;
    int cnt = 0;
    for (int ch = 0; ch < 4; ++ch) {
      float v = Ag[(size_t)r*NN + ch*64 + lane];
      unsigned long long mask = __ballot(v > 0.5f);
      int pos = __popcll(mask & ((1ull << lane) - 1ull));
      if (v > 0.5f && cnt + pos < MAXNB) nb[cnt + pos] = (unsigned char)(ch*64 + lane);
      cnt += __popcll(mask);
    }
    if (lane == 0) {
      cnt0[g*NN + r] = cnt < MAXNB ? cnt : MAXNB;
      float nv = rsqrtf(fmaxf((float)cnt, 1.0f));
      norm0[g*NN + r] = nv;
      snorm[r] = nv;
    }
  }
  __syncthreads();

  // ---- phase 1: MFMA spmm ----
  f32x16 acc[2][4];
  #pragma unroll
  for (int i = 0; i < 2; ++i)
    #pragma unroll
    for (int j = 0; j < 4; ++j) acc[i][j] = (f32x16)0.0f;

  int xn   = t & 127;
  int kg16 = (t >> 7) * 16;

  for (int kt = 0; kt < NN; kt += 32) {
    float4 af[2][2][2];
    #pragma unroll
    for (int mt = 0; mt < 2; ++mt)
      #pragma unroll
      for (int s = 0; s < 2; ++s) {
        const float* ap = Ag + (size_t)(wave*64 + mt*32 + lm)*NN + kt + s*16 + lh*8;
        af[mt][s][0] = *reinterpret_cast<const float4*>(ap);
        af[mt][s][1] = *reinterpret_cast<const float4*>(ap + 4);
      }

    #pragma unroll
    for (int c = 0; c < 4; ++c) {
      U64pack p0, p1, p2;
      #pragma unroll
      for (int kk = 0; kk < 4; ++kk) {
        int m = kt + kg16 + c*4 + kk;
        float x = Xg[(size_t)m*FF + xn] * snorm[m];
        unsigned short h1 = f2bf(x);  float r1 = x - bf2f(h1);
        unsigned short h2 = f2bf(r1); float r2 = r1 - bf2f(h2);
        unsigned short h3 = f2bf(r2);
        p0.us[kk] = h1; p1.us[kk] = h2; p2.us[kk] = h3;
      }
      int base = xn*9 + kg16/4 + c;
      xs[base        ] = p0.u;
      xs[base + 128*9] = p1.u;
      xs[base + 256*9] = p2.u;
    }
    __syncthreads();

    Frag8 afr[2][2];
    #pragma unroll
    for (int mt = 0; mt < 2; ++mt)
      #pragma unroll
      for (int s = 0; s < 2; ++s) {
        const float* fv = &af[mt][s][0].x;
        #pragma unroll
        for (int j = 0; j < 8; ++j) afr[mt][s].us[j] = f2bf(fv[j]);
      }

    #pragma unroll
    for (int s = 0; s < 2; ++s)
      #pragma unroll
      for (int sp = 0; sp < 3; ++sp)
        #pragma unroll
        for (int nt = 0; nt < 4; ++nt) {
          int n = nt*32 + lm;
          int idx = (sp*128 + n)*9 + 4*s + 2*lh;
          Frag8 bf_;
          bf_.u64[0] = xs[idx];
          bf_.u64[1] = xs[idx + 1];
          #pragma unroll
          for (int mt = 0; mt < 2; ++mt)
            acc[mt][nt] = __builtin_amdgcn_mfma_f32_32x32x16_bf16(
                afr[mt][s].v, bf_.v, acc[mt][nt], 0, 0, 0);
        }
    __syncthreads();
  }

  #pragma unroll
  for (int mt = 0; mt < 2; ++mt)
    #pragma unroll
    for (int nt = 0; nt < 4; ++nt)
      #pragma unroll
      for (int r = 0; r < 16; ++r) {
        int row = wave*64 + mt*32 + (r & 3) + 8*(r >> 2) + 4*lh;
        int col = nt*32 + lm;
        T0[((size_t)g*NN + row)*FF + col] = acc[mt][nt][r];
      }
}

// ---------------- MFMA GEMM, LDS-free: one wave = 32 rows x 256 cols ----------------
// A (Tmat) split 3-way in-register; B from pre-split k-major planes via direct 16B
// fragment loads (L1/L2-resident, identical across all blocks). 6 products: err ~2^-26.
template<int K, bool WRITE_X>
__global__ __launch_bounds__(64, 2) void k_gemm_mfma(
    const float* __restrict__ Tmat, const unsigned short* __restrict__ Wk,
    const float* __restrict__ normv, const float* __restrict__ bias,
    const float* __restrict__ Ws, float* __restrict__ xout, float* __restrict__ hs) {
  int lane = threadIdx.x;
  int lm = lane & 31, lh = lane >> 5;
  int rowbase = blockIdx.x * 32;

  f32x16 acc[8];
  #pragma unroll
  for (int nt = 0; nt < 8; ++nt) acc[nt] = (f32x16)0.0f;

  for (int kt = 0; kt < K; kt += 32) {
    float4 af[2][2];
    #pragma unroll
    for (int s = 0; s < 2; ++s) {
      const float* ap = Tmat + (size_t)(rowbase + lm)*K + kt + s*16 + lh*8;
      af[s][0] = *reinterpret_cast<const float4*>(ap);
      af[s][1] = *reinterpret_cast<const float4*>(ap + 4);
    }
    Frag8 afr[2][3];
    #pragma unroll
    for (int s = 0; s < 2; ++s) {
      const float* fv = &af[s][0].x;
      #pragma unroll
      for (int j = 0; j < 8; ++j) {
        float x = fv[j];
        unsigned short h1 = f2bf(x);  float r1 = x - bf2f(h1);
        unsigned short h2 = f2bf(r1); float r2 = r1 - bf2f(h2);
        afr[s][0].us[j] = h1; afr[s][1].us[j] = h2; afr[s][2].us[j] = f2bf(r2);
      }
    }

    #pragma unroll
    for (int s = 0; s < 2; ++s)
      #pragma unroll
      for (int nt = 0; nt < 8; ++nt) {
        const unsigned short* bp = Wk + (size_t)(nt*32 + lm)*K + kt + s*16 + lh*8;
        Frag8 b0_, b1_, b2_;
        b0_.v = *reinterpret_cast<const bf16x8*>(bp);
        b1_.v = *reinterpret_cast<const bf16x8*>(bp + (size_t)DD*K);
        b2_.v = *reinterpret_cast<const bf16x8*>(bp + (size_t)2*DD*K);
        acc[nt] = __builtin_amdgcn_mfma_f32_32x32x16_bf16(afr[s][0].v, b0_.v, acc[nt], 0,0,0);
        acc[nt] = __builtin_amdgcn_mfma_f32_32x32x16_bf16(afr[s][0].v, b1_.v, acc[nt], 0,0,0);
        acc[nt] = __builtin_amdgcn_mfma_f32_32x32x16_bf16(afr[s][1].v, b0_.v, acc[nt], 0,0,0);
        acc[nt] = __builtin_amdgcn_mfma_f32_32x32x16_bf16(afr[s][0].v, b2_.v, acc[nt], 0,0,0);
        acc[nt] = __builtin_amdgcn_mfma_f32_32x32x16_bf16(afr[s][2].v, b0_.v, acc[nt], 0,0,0);
        acc[nt] = __builtin_amdgcn_mfma_f32_32x32x16_bf16(afr[s][1].v, b1_.v, acc[nt], 0,0,0);
      }
  }

  // epilogue: C/D layout col=lane&31, row=(reg&3)+8*(reg>>2)+4*(lane>>5)
  float bcol[8], wcol[8];
  #pragma unroll
  for (int nt = 0; nt < 8; ++nt) { int col = nt*32 + lm; bcol[nt] = bias[col]; wcol[nt] = Ws[col]; }
  float hsum[16];
  #pragma unroll
  for (int r = 0; r < 16; ++r) {
    int row = rowbase + (r & 3) + 8*(r >> 2) + 4*lh;
    float nv = normv[row];
    float hp = 0.f;
    #pragma unroll
    for (int nt = 0; nt < 8; ++nt) {
      float val = lrelu(nv*acc[nt][r] + bcol[nt]);
      if (WRITE_X) xout[(size_t)row*DD + nt*32 + lm] = val;
      hp += val*wcol[nt];
    }
    hsum[r] = hp;
  }
  #pragma unroll
  for (int off = 1; off <= 16; off <<= 1)
    #pragma unroll
    for (int r = 0; r < 16; ++r) hsum[r] += __shfl_xor(hsum[r], off);
  if (lm == 0)
    #pragma unroll
    for (int r = 0; r < 16; ++r) {
      int row = rowbase + (r & 3) + 8*(r >> 2) + 4*lh;
      hs[row] = normv[row]*hsum[r];
    }
}

// ---------------- score layer0 (sparse) ----------------
__global__ void k_score0(const float* __restrict__ hs, const int* __restrict__ cnt0,
                         const unsigned char* __restrict__ nbr0, const float* __restrict__ norm0,
                         const float* __restrict__ bs, float* __restrict__ score) {
  int g = blockIdx.x; int r = threadIdx.x;
  int cnt = cnt0[g*NN + r];
  const unsigned char* nb = nbr0 + ((size_t)g*NN + r)*MAXNB;
  float s = 0.f;
  for (int j = 0; j < cnt; ++j) s += hs[g*NN + nb[j]];
  score[g*NN + r] = norm0[g*NN + r]*s + bs[0];
}

// ---------------- score layers 1/2 (dense small) ----------------
template<int n>
__global__ void k_score_dense(const float* __restrict__ a, const float* __restrict__ hs,
                              const float* __restrict__ normv, const float* __restrict__ bs,
                              float* __restrict__ score) {
  int row = blockIdx.x*blockDim.x + threadIdx.x;
  if (row >= GG*n) return;
  int g = row / n;
  const float* ar = a + (size_t)g*n*n + (size_t)(row - g*n)*n;
  float s = 0.f;
  for (int m = 0; m < n; ++m) s += ar[m]*hs[g*n + m];
  score[row] = normv[row]*s + bs[0];
}

// ---------------- top-k per graph (one wave per graph), ties -> lower index ----------------
template<int n, int k>
__global__ void k_topk(const float* __restrict__ score, int* __restrict__ idx_out,
                       float* __restrict__ tv_out) {
  int g = blockIdx.x*4 + (threadIdx.x >> 6);
  int lane = threadIdx.x & 63;
  constexpr int E = (n + 63)/64;
  float s[E]; int si[E];
  #pragma unroll
  for (int e = 0; e < E; ++e) {
    int i = e*64 + lane;
    if (i < n) { s[e] = score[(size_t)g*n + i]; si[e] = i; }
    else { s[e] = -INFINITY; si[e] = 1 << 30; }
  }
  for (int kk = 0; kk < k; ++kk) {
    float bs_ = -INFINITY; int bi = 1 << 30;
    #pragma unroll
    for (int e = 0; e < E; ++e)
      if (s[e] > bs_ || (s[e] == bs_ && si[e] < bi)) { bs_ = s[e]; bi = si[e]; }
    for (int off = 32; off; off >>= 1) {
      float os = __shfl_xor(bs_, off);
      int oi = __shfl_xor(bi, off);
      if (os > bs_ || (os == bs_ && oi < bi)) { bs_ = os; bi = oi; }
    }
    if (lane == 0) { idx_out[(size_t)g*k + kk] = bi; tv_out[(size_t)g*k + kk] = tanhf(bs_); }
    #pragma unroll
    for (int e = 0; e < E; ++e) if (si[e] == bi) s[e] = -INFINITY;
  }
}

// ---------------- layer0 selection: recompute x1 rows for top-32, gate, readout, a1 gather ----------------
__global__ void k_sel0(const float* __restrict__ T0, const float* __restrict__ W0,
                       const float* __restrict__ norm0, const float* __restrict__ b0,
                       const int* __restrict__ idx, const float* __restrict__ tv,
                       const float* __restrict__ adj, float* __restrict__ x_sel,
                       float* __restrict__ a1, float* __restrict__ merged) {
  __shared__ float sT[KS0*FF];     // 16 KB
  __shared__ int sidx[KS0]; __shared__ float stv[KS0]; __shared__ float snv[KS0];
  int g = blockIdx.x, t = threadIdx.x;
  if (t < KS0) { sidx[t] = idx[g*KS0 + t]; stv[t] = tv[g*KS0 + t]; }
  __syncthreads();
  if (t < KS0) snv[t] = norm0[g*NN + sidx[t]];
  #pragma unroll
  for (int i = 0; i < 16; ++i) {
    int e = t + i*256, r = e >> 7, c = e & 127;
    sT[e] = T0[((size_t)g*NN + sidx[r])*FF + c];
  }
  __syncthreads();
  float sum[KS0];
  #pragma unroll
  for (int j = 0; j < KS0; ++j) sum[j] = 0.f;
  for (int k = 0; k < FF; k += 4) {
    float4 w;
    w.x = W0[(size_t)(k+0)*DD + t]; w.y = W0[(size_t)(k+1)*DD + t];
    w.z = W0[(size_t)(k+2)*DD + t]; w.w = W0[(size_t)(k+3)*DD + t];
    #pragma unroll
    for (int j = 0; j < KS0; ++j) {
      float4 tv4 = *reinterpret_cast<const float4*>(&sT[j*FF + k]);
      sum[j] += tv4.x*w.x + tv4.y*w.y + tv4.z*w.z + tv4.w*w.w;
    }
  }
  float b = b0[t];
  float s = 0.f, mx = -INFINITY;
  #pragma unroll
  for (int j = 0; j < KS0; ++j) {
    float val = lrelu(snv[j]*sum[j] + b) * stv[j];
    x_sel[((size_t)g*KS0 + j)*DD + t] = val;
    s += val; mx = fmaxf(mx, val);
  }
  merged[(size_t)g*1536 + t] = s;
  merged[(size_t)g*1536 + 256 + t] = mx;
  for (int e = t; e < KS0*KS0; e += 256) {
    int r = e >> 5, c = e & 31;
    a1[(size_t)g*KS0*KS0 + e] = adj[(size_t)g*NN*NN + (size_t)sidx[r]*NN + sidx[c]];
  }
}

// ---------------- gathers + readouts (layers 1/2) ----------------
__global__ void k_gather1(const float* __restrict__ x2, const float* __restrict__ a1,
                          const int* __restrict__ idx, const float* __restrict__ tv,
                          float* __restrict__ x_sel2, float* __restrict__ a2,
                          float* __restrict__ merged) {
  __shared__ int sidx[KS1]; __shared__ float stv[KS1];
  int g = blockIdx.x; int t = threadIdx.x;
  if (t < KS1) { sidx[t] = idx[g*KS1 + t]; stv[t] = tv[g*KS1 + t]; }
  __syncthreads();
  float sum = 0.f, mx = -INFINITY;
  for (int j = 0; j < KS1; ++j) {
    float v = x2[((size_t)g*KS0 + sidx[j])*DD + t] * stv[j];
    x_sel2[((size_t)g*KS1 + j)*DD + t] = v;
    sum += v; mx = fmaxf(mx, v);
  }
  merged[(size_t)g*1536 + 512 + t] = sum;
  merged[(size_t)g*1536 + 768 + t] = mx;
  {
    int r = t >> 4, c = t & 15;
    a2[(size_t)g*KS1*KS1 + t] = a1[(size_t)g*KS0*KS0 + sidx[r]*KS0 + sidx[c]];
  }
}

__global__ void k_gather2(const float* __restrict__ x3, const int* __restrict__ idx,
                          const float* __restrict__ tv, float* __restrict__ merged) {
  __shared__ int sidx[KS2]; __shared__ float stv[KS2];
  int g = blockIdx.x; int t = threadIdx.x;
  if (t < KS2) { sidx[t] = idx[g*KS2 + t]; stv[t] = tv[g*KS2 + t]; }
  __syncthreads();
  float sum = 0.f, mx = -INFINITY;
  for (int j = 0; j < KS2; ++j) {
    float v = x3[((size_t)g*KS1 + sidx[j])*DD + t] * stv[j];
    sum += v; mx = fmaxf(mx, v);
  }
  merged[(size_t)g*1536 + 1024 + t] = sum;
  merged[(size_t)g*1536 + 1280 + t] = mx;
}

// ---------------- dense small spmm: norm from a, T = a @ (x*norm) ----------------
template<int n>
__global__ void k_spmm_dense(const float* __restrict__ a, const float* __restrict__ x,
                             float* __restrict__ normv, float* __restrict__ T) {
  __shared__ float sa[n*n];
  __shared__ float snorm[n];
  __shared__ float sx[n*DD];
  int g = blockIdx.x; int t = threadIdx.x;
  for (int e = t; e < n*n; e += 256) sa[e] = a[(size_t)g*n*n + e];
  __syncthreads();
  if (t < n) {
    float dg = 0.f;
    for (int m = 0; m < n; ++m) dg += sa[t*n + m];
    float nv = rsqrtf(fmaxf(dg, 1.f));
    snorm[t] = nv; normv[g*n + t] = nv;
  }
  __syncthreads();
  for (int e = t; e < n*DD; e += 256) sx[e] = x[(size_t)g*n*DD + e] * snorm[e >> 8];
  __syncthreads();
  float acc[n];
  #pragma unroll
  for (int r = 0; r < n; ++r) acc[r] = 0.f;
  for (int m = 0; m < n; ++m) {
    float xv = sx[m*DD + t];
    #pragma unroll
    for (int r = 0; r < n; ++r) acc[r] += sa[r*n + m]*xv;
  }
  for (int r = 0; r < n; ++r) T[((size_t)g*n + r)*DD + t] = acc[r];
}

// ---------------- final MLP ----------------
__global__ void k_mlp(const float* __restrict__ merged, const float* __restrict__ Wd1,
                      const float* __restrict__ bd1, const float* __restrict__ Wd2,
                      const float* __restrict__ bd2, float* __restrict__ out) {
  __shared__ float sm[1536];
  __shared__ float sh[128];
  int g = blockIdx.x; int t = threadIdx.x;     // 128 threads
  for (int i = t; i < 1536; i += 128) sm[i] = merged[(size_t)g*1536 + i];
  __syncthreads();
  float acc = 0.f;
  for (int k = 0; k < 1536; ++k) acc += sm[k]*Wd1[(size_t)k*128 + t];
  sh[t] = lrelu(acc + bd1[t]);
  __syncthreads();
  if (t < 2) {
    float o = 0.f;
    for (int k = 0; k < 128; ++k) o += sh[k]*Wd2[k*2 + t];
    out[(size_t)g*2 + t] = 1.f/(1.f + expf(-(o + bd2[t])));
  }
}

extern "C" void kernel_launch(void* const* d_in, const int* in_sizes, int n_in,
                              void* d_out, int out_size, void* d_ws, size_t ws_size,
                              hipStream_t stream) {
  const float* feat = (const float*)d_in[0];
  const float* adj  = (const float*)d_in[1];
  const float* W0 = (const float*)d_in[2];  const float* b0  = (const float*)d_in[3];
  const float* Ws0= (const float*)d_in[4];  const float* bs0 = (const float*)d_in[5];
  const float* W1 = (const float*)d_in[6];  const float* b1  = (const float*)d_in[7];
  const float* Ws1= (const float*)d_in[8];  const float* bs1 = (const float*)d_in[9];
  const float* W2 = (const float*)d_in[10]; const float* b2  = (const float*)d_in[11];
  const float* Ws2= (const float*)d_in[12]; const float* bs2 = (const float*)d_in[13];
  const float* Wd1= (const float*)d_in[14]; const float* bd1 = (const float*)d_in[15];
  const float* Wd2= (const float*)d_in[16]; const float* bd2 = (const float*)d_in[17];
  float* out = (float*)d_out;

  char* ws = (char*)d_ws;
  size_t off = 0;
  auto alloc = [&](size_t bytes) -> char* {
    char* p = ws + off; off += (bytes + 255) & ~(size_t)255; return p;
  };
  float* norm0 = (float*)alloc((size_t)GG*NN*4);
  int*   cnt0  = (int*)  alloc((size_t)GG*NN*4);
  unsigned char* nbr0 = (unsigned char*)alloc((size_t)GG*NN*MAXNB);
  float* hs0   = (float*)alloc((size_t)GG*NN*4);
  float* score0= (float*)alloc((size_t)GG*NN*4);
  int*   idx0  = (int*)  alloc((size_t)GG*KS0*4);
  float* tv0   = (float*)alloc((size_t)GG*KS0*4);
  float* norm1 = (float*)alloc((size_t)GG*KS0*4);
  float* hs1   = (float*)alloc((size_t)GG*KS0*4);
  float* score1= (float*)alloc((size_t)GG*KS0*4);
  int*   idx1  = (int*)  alloc((size_t)GG*KS1*4);
  float* tv1   = (float*)alloc((size_t)GG*KS1*4);
  float* norm2 = (float*)alloc((size_t)GG*KS1*4);
  float* hs2   = (float*)alloc((size_t)GG*KS1*4);
  float* score2= (float*)alloc((size_t)GG*KS1*4);
  int*   idx2  = (int*)  alloc((size_t)GG*KS2*4);
  float* tv2   = (float*)alloc((size_t)GG*KS2*4);
  float* merged= (float*)alloc((size_t)GG*1536*4);
  unsigned short* W0s = (unsigned short*)alloc((size_t)3*FF*DD*2);
  unsigned short* W1s = (unsigned short*)alloc((size_t)3*DD*DD*2);
  unsigned short* W2s = (unsigned short*)alloc((size_t)3*DD*DD*2);
  char* regA = alloc((size_t)GG*NN*FF*4);   // 128 MB: T0, later T1
  char* regB = alloc((size_t)GG*160*DD*4);  // ~160 MB: layer1+ buffers

  float* T0 = (float*)regA;
  float* T1 = (float*)regA;                 // reuse after k_sel0 consumed T0
  float* x_sel1 = (float*)regB;                                      // 32 MB
  float* a1     = (float*)(regB + (size_t)GG*KS0*DD*4);              //  4 MB
  float* x2     = (float*)((char*)a1     + (size_t)GG*KS0*KS0*4);    // 32 MB
  float* x_sel2 = (float*)((char*)x2     + (size_t)GG*KS0*DD*4);     // 16 MB
  float* a2     = (float*)((char*)x_sel2 + (size_t)GG*KS1*DD*4);     //  1 MB
  float* T2     = (float*)((char*)a2     + (size_t)GG*KS1*KS1*4);    // 16 MB
  float* x3     = (float*)((char*)T2     + (size_t)GG*KS1*DD*4);     // 16 MB

  // ---- weight pre-split (k-major fragment layout) ----
  k_splitW<<<(FF*DD + 255)/256, 256, 0, stream>>>(W0, W0s, FF);
  k_splitW<<<(DD*DD + 255)/256, 256, 0, stream>>>(W1, W1s, DD);
  k_splitW<<<(DD*DD + 255)/256, 256, 0, stream>>>(W2, W2s, DD);

  // ---- layer 0 ----
  k_spmm_mfma<<<GG, 256, 0, stream>>>(adj, feat, norm0, cnt0, nbr0, T0);
  k_gemm_mfma<FF, false><<<GG*NN/32, 64, 0, stream>>>(T0, W0s, norm0, b0, Ws0, nullptr, hs0);
  k_score0<<<GG, 256, 0, stream>>>(hs0, cnt0, nbr0, norm0, bs0, score0);
  k_topk<NN, KS0><<<GG/4, 256, 0, stream>>>(score0, idx0, tv0);
  k_sel0<<<GG, 256, 0, stream>>>(T0, W0, norm0, b0, idx0, tv0, adj, x_sel1, a1, merged);

  // ---- layer 1 ----
  k_spmm_dense<KS0><<<GG, 256, 0, stream>>>(a1, x_sel1, norm1, T1);
  k_gemm_mfma<DD, true><<<GG*KS0/32, 64, 0, stream>>>(T1, W1s, norm1, b1, Ws1, x2, hs1);
  k_score_dense<KS0><<<(GG*KS0 + 255)/256, 256, 0, stream>>>(a1, hs1, norm1, bs1, score1);
  k_topk<KS0, KS1><<<GG/4, 256, 0, stream>>>(score1, idx1, tv1);
  k_gather1<<<GG, 256, 0, stream>>>(x2, a1, idx1, tv1, x_sel2, a2, merged);

  // ---- layer 2 ----
  k_spmm_dense<KS1><<<GG, 256, 0, stream>>>(a2, x_sel2, norm2, T2);
  k_gemm_mfma<DD, true><<<GG*KS1/32, 64, 0, stream>>>(T2, W2s, norm2, b2, Ws2, x3, hs2);
  k_score_dense<KS1><<<(GG*KS1 + 255)/256, 256, 0, stream>>>(a2, hs2, norm2, bs2, score2);
  k_topk<KS1, KS2><<<GG/4, 256, 0, stream>>>(score2, idx2, tv2);
  k_gather2<<<GG, 256, 0, stream>>>(x3, idx2, tv2, merged);

  // ---- MLP head ----
  k_mlp<<<GG, 128, 0, stream>>>(merged, Wd1, bd1, Wd2, bd2, out);

  (void)in_sizes; (void)n_in; (void)out_size; (void)ws_size;
}

// Round 5
// 1307.262 us; speedup vs baseline: 1.1990x; 1.1990x over previous
//
#include <hip/hip_runtime.h>
#include <math.h>

constexpr int GG  = 1024;   // graphs
constexpr int NN  = 256;    // nodes layer0
constexpr int FF  = 128;    // input feat
constexpr int DD  = 256;    // hidden
constexpr int KS0 = 32, KS1 = 16, KS2 = 8;

__device__ __forceinline__ float lrelu(float x){ return x >= 0.f ? x : 0.01f*x; }

// bf16 helpers
__device__ __forceinline__ unsigned short f2bf(float f) {
  unsigned u = __float_as_uint(f);
  unsigned r = (u + 0x7FFFu + ((u >> 16) & 1u)) >> 16;
  return (unsigned short)r;
}
__device__ __forceinline__ float bf2f(unsigned short h) {
  return __uint_as_float(((unsigned)h) << 16);
}

typedef __attribute__((ext_vector_type(8)))  __bf16 bf16x8;
typedef __attribute__((ext_vector_type(16))) float  f32x16;

union Frag8 { unsigned short us[8]; unsigned long long u64[2]; bf16x8 v; };

// ---------------- pre-split weights into 3 bf16 planes, FRAG-BLOCKED layout ----------------
// out[sp*DD*K + e] where e = ((((nt*(K/32) + kti)*2 + s)*64 + lane)*8 + j)
// lane = (n&31) + 32*((k>>3)&1); a wave's B-fragment load is 1KB contiguous.
__global__ void k_splitW(const float* __restrict__ W, unsigned short* __restrict__ out, int K) {
  int e = blockIdx.x*256 + threadIdx.x;
  if (e >= DD*K) return;
  int j   = e & 7;
  int l   = (e >> 3) & 63;
  int s   = (e >> 9) & 1;
  int kti = (e >> 10) % (K >> 5);
  int nt  = e / ((K >> 5) << 10);
  int n = nt*32 + (l & 31);
  int k = kti*32 + s*16 + ((l >> 5) << 3) + j;
  float x = W[(size_t)k*DD + n];
  unsigned short h1 = f2bf(x);  float r1 = x - bf2f(h1);
  unsigned short h2 = f2bf(r1); float r2 = r1 - bf2f(h2);
  unsigned short h3 = f2bf(r2);
  out[e] = h1; out[DD*K + e] = h2; out[2*DD*K + e] = h3;
}

// ---------------- norm0 = rsqrt(max(rowsum(adj),1)) — wave per row, fully coalesced ----------------
__global__ void k_norm(const float* __restrict__ adj, float* __restrict__ norm0) {
  int row = blockIdx.x*4 + (threadIdx.x >> 6);
  int lane = threadIdx.x & 63;
  float4 v = *reinterpret_cast<const float4*>(adj + (size_t)row*NN + lane*4);
  float s = v.x + v.y + v.z + v.w;
  for (int off = 32; off; off >>= 1) s += __shfl_xor(s, off);
  if (lane == 0) norm0[row] = rsqrtf(fmaxf(s, 1.0f));
}

// ---------------- Xt[sp][g][n][k] = split_sp(X[g][k][n] * norm[k]), k-contiguous ----------------
__global__ void k_xsplit(const float* __restrict__ feat, const float* __restrict__ norm0,
                         unsigned short* __restrict__ Xt) {
  __shared__ unsigned short ls[3*128*32];   // 24 KB
  __shared__ float snorm[NN];
  int g = blockIdx.x, t = threadIdx.x;
  snorm[t] = norm0[g*NN + t];
  __syncthreads();
  const float* Xg = feat + (size_t)g*NN*FF;
  for (int chunk = 0; chunk < 8; ++chunk) {
    #pragma unroll
    for (int i = 0; i < 16; ++i) {
      int e = t + i*256;
      int m = chunk*32 + (e >> 7), c = e & 127;
      float x = Xg[(size_t)m*FF + c] * snorm[m];
      unsigned short h1 = f2bf(x);  float r1 = x - bf2f(h1);
      unsigned short h2 = f2bf(r1); float r2 = r1 - bf2f(h2);
      unsigned short h3 = f2bf(r2);
      int mm = m & 31;
      ls[(0*128 + c)*32 + mm] = h1;
      ls[(1*128 + c)*32 + mm] = h2;
      ls[(2*128 + c)*32 + mm] = h3;
    }
    __syncthreads();
    int n = t >> 1, half = t & 1;
    #pragma unroll
    for (int sp = 0; sp < 3; ++sp) {
      const ulonglong2* src = reinterpret_cast<const ulonglong2*>(&ls[((sp*128 + n)*32) + half*16]);
      size_t dst = (((size_t)sp*GG + g)*128 + n)*256 + chunk*32 + half*16;
      ulonglong2* d = reinterpret_cast<ulonglong2*>(Xt + dst);
      d[0] = src[0];
      d[1] = src[1];
    }
    __syncthreads();
  }
}

// ---------------- T0 = A @ Xn via bf16 MFMA: LDS-free, barrier-free ----------------
// A-frags from adj (binary -> exact bf16); B-frags = contiguous 16B loads from Xt.
__global__ __launch_bounds__(256, 2) void k_spmm_mfma(
    const float* __restrict__ adj, const unsigned short* __restrict__ Xt,
    float* __restrict__ T0) {
  int g = blockIdx.x;
  int t = threadIdx.x;
  int lane = t & 63, wave = t >> 6;
  int lm = lane & 31, lh = lane >> 5;

  const float* Ag = adj + (size_t)g*NN*NN;

  f32x16 acc[2][4];
  #pragma unroll
  for (int i = 0; i < 2; ++i)
    #pragma unroll
    for (int j = 0; j < 4; ++j) acc[i][j] = (f32x16)0.0f;

  for (int kt = 0; kt < NN; kt += 32) {
    // A fragments: rows owned exclusively by this wave
    Frag8 afr[2][2];
    #pragma unroll
    for (int mt = 0; mt < 2; ++mt)
      #pragma unroll
      for (int s = 0; s < 2; ++s) {
        const float* ap = Ag + (size_t)(wave*64 + mt*32 + lm)*NN + kt + s*16 + lh*8;
        float4 a0 = *reinterpret_cast<const float4*>(ap);
        float4 a1 = *reinterpret_cast<const float4*>(ap + 4);
        afr[mt][s].us[0] = f2bf(a0.x); afr[mt][s].us[1] = f2bf(a0.y);
        afr[mt][s].us[2] = f2bf(a0.z); afr[mt][s].us[3] = f2bf(a0.w);
        afr[mt][s].us[4] = f2bf(a1.x); afr[mt][s].us[5] = f2bf(a1.y);
        afr[mt][s].us[6] = f2bf(a1.z); afr[mt][s].us[7] = f2bf(a1.w);
      }

    #pragma unroll
    for (int s = 0; s < 2; ++s)
      #pragma unroll
      for (int nt = 0; nt < 4; ++nt) {
        size_t bbase = ((size_t)g*128 + nt*32 + lm)*256 + kt + s*16 + lh*8;
        Frag8 b0_, b1_, b2_;
        b0_.v = *reinterpret_cast<const bf16x8*>(Xt + bbase);
        b1_.v = *reinterpret_cast<const bf16x8*>(Xt + (size_t)GG*128*256 + bbase);
        b2_.v = *reinterpret_cast<const bf16x8*>(Xt + (size_t)2*GG*128*256 + bbase);
        #pragma unroll
        for (int mt = 0; mt < 2; ++mt) {
          acc[mt][nt] = __builtin_amdgcn_mfma_f32_32x32x16_bf16(afr[mt][s].v, b0_.v, acc[mt][nt], 0,0,0);
          acc[mt][nt] = __builtin_amdgcn_mfma_f32_32x32x16_bf16(afr[mt][s].v, b1_.v, acc[mt][nt], 0,0,0);
          acc[mt][nt] = __builtin_amdgcn_mfma_f32_32x32x16_bf16(afr[mt][s].v, b2_.v, acc[mt][nt], 0,0,0);
        }
      }
  }

  // epilogue: C/D layout col=lane&31, row=(reg&3)+8*(reg>>2)+4*(lane>>5)
  #pragma unroll
  for (int mt = 0; mt < 2; ++mt)
    #pragma unroll
    for (int nt = 0; nt < 4; ++nt)
      #pragma unroll
      for (int r = 0; r < 16; ++r) {
        int row = wave*64 + mt*32 + (r & 3) + 8*(r >> 2) + 4*lh;
        int col = nt*32 + lm;
        T0[((size_t)g*NN + row)*FF + col] = acc[mt][nt][r];
      }
}

// ---------------- MFMA GEMM, LDS-free: one wave = 32 rows x 256 cols ----------------
template<int K, bool WRITE_X>
__global__ __launch_bounds__(64, 2) void k_gemm_mfma(
    const float* __restrict__ Tmat, const unsigned short* __restrict__ Wk,
    const float* __restrict__ normv, const float* __restrict__ bias,
    const float* __restrict__ Ws, float* __restrict__ xout, float* __restrict__ hs) {
  int lane = threadIdx.x;
  int lm = lane & 31, lh = lane >> 5;
  int rowbase = blockIdx.x * 32;

  f32x16 acc[8];
  #pragma unroll
  for (int nt = 0; nt < 8; ++nt) acc[nt] = (f32x16)0.0f;

  for (int kt = 0; kt < K; kt += 32) {
    float4 af[2][2];
    #pragma unroll
    for (int s = 0; s < 2; ++s) {
      const float* ap = Tmat + (size_t)(rowbase + lm)*K + kt + s*16 + lh*8;
      af[s][0] = *reinterpret_cast<const float4*>(ap);
      af[s][1] = *reinterpret_cast<const float4*>(ap + 4);
    }
    Frag8 afr[2][3];
    #pragma unroll
    for (int s = 0; s < 2; ++s) {
      const float* fv = &af[s][0].x;
      #pragma unroll
      for (int j = 0; j < 8; ++j) {
        float x = fv[j];
        unsigned short h1 = f2bf(x);  float r1 = x - bf2f(h1);
        unsigned short h2 = f2bf(r1); float r2 = r1 - bf2f(h2);
        afr[s][0].us[j] = h1; afr[s][1].us[j] = h2; afr[s][2].us[j] = f2bf(r2);
      }
    }

    #pragma unroll
    for (int s = 0; s < 2; ++s)
      #pragma unroll
      for (int nt = 0; nt < 8; ++nt) {
        size_t boff = ((((size_t)nt*(K >> 5) + (kt >> 5))*2 + s)*64 + lane)*8;
        Frag8 b0_, b1_, b2_;
        b0_.v = *reinterpret_cast<const bf16x8*>(Wk + boff);
        b1_.v = *reinterpret_cast<const bf16x8*>(Wk + (size_t)DD*K + boff);
        b2_.v = *reinterpret_cast<const bf16x8*>(Wk + (size_t)2*DD*K + boff);
        acc[nt] = __builtin_amdgcn_mfma_f32_32x32x16_bf16(afr[s][0].v, b0_.v, acc[nt], 0,0,0);
        acc[nt] = __builtin_amdgcn_mfma_f32_32x32x16_bf16(afr[s][0].v, b1_.v, acc[nt], 0,0,0);
        acc[nt] = __builtin_amdgcn_mfma_f32_32x32x16_bf16(afr[s][1].v, b0_.v, acc[nt], 0,0,0);
        acc[nt] = __builtin_amdgcn_mfma_f32_32x32x16_bf16(afr[s][0].v, b2_.v, acc[nt], 0,0,0);
        acc[nt] = __builtin_amdgcn_mfma_f32_32x32x16_bf16(afr[s][2].v, b0_.v, acc[nt], 0,0,0);
        acc[nt] = __builtin_amdgcn_mfma_f32_32x32x16_bf16(afr[s][1].v, b1_.v, acc[nt], 0,0,0);
      }
  }

  float bcol[8], wcol[8];
  #pragma unroll
  for (int nt = 0; nt < 8; ++nt) { int col = nt*32 + lm; bcol[nt] = bias[col]; wcol[nt] = Ws[col]; }
  float hsum[16];
  #pragma unroll
  for (int r = 0; r < 16; ++r) {
    int row = rowbase + (r & 3) + 8*(r >> 2) + 4*lh;
    float nv = normv[row];
    float hp = 0.f;
    #pragma unroll
    for (int nt = 0; nt < 8; ++nt) {
      float val = lrelu(nv*acc[nt][r] + bcol[nt]);
      if (WRITE_X) xout[(size_t)row*DD + nt*32 + lm] = val;
      hp += val*wcol[nt];
    }
    hsum[r] = hp;
  }
  #pragma unroll
  for (int off = 1; off <= 16; off <<= 1)
    #pragma unroll
    for (int r = 0; r < 16; ++r) hsum[r] += __shfl_xor(hsum[r], off);
  if (lm == 0)
    #pragma unroll
    for (int r = 0; r < 16; ++r) {
      int row = rowbase + (r & 3) + 8*(r >> 2) + 4*lh;
      hs[row] = normv[row]*hsum[r];
    }
}

// ---------------- score0 dense: score[c] = norm[c]*sum_r adj[r][c]*hs[r] + bs (adj symmetric) ----------------
__global__ void k_score0(const float* __restrict__ adj, const float* __restrict__ hs,
                         const float* __restrict__ norm0, const float* __restrict__ bs,
                         float* __restrict__ score) {
  __shared__ float sh[NN];
  int g = blockIdx.x, t = threadIdx.x;
  sh[t] = hs[g*NN + t];
  __syncthreads();
  const float* A = adj + (size_t)g*NN*NN;
  float s = 0.f;
  #pragma unroll 8
  for (int r = 0; r < NN; ++r) s += A[(size_t)r*NN + t] * sh[r];
  score[g*NN + t] = norm0[g*NN + t]*s + bs[0];
}

// ---------------- score layers 1/2 (dense small) ----------------
template<int n>
__global__ void k_score_dense(const float* __restrict__ a, const float* __restrict__ hs,
                              const float* __restrict__ normv, const float* __restrict__ bs,
                              float* __restrict__ score) {
  int row = blockIdx.x*blockDim.x + threadIdx.x;
  if (row >= GG*n) return;
  int g = row / n;
  const float* ar = a + (size_t)g*n*n + (size_t)(row - g*n)*n;
  float s = 0.f;
  for (int m = 0; m < n; ++m) s += ar[m]*hs[g*n + m];
  score[row] = normv[row]*s + bs[0];
}

// ---------------- top-k per graph (one wave per graph), ties -> lower index ----------------
template<int n, int k>
__global__ void k_topk(const float* __restrict__ score, int* __restrict__ idx_out,
                       float* __restrict__ tv_out) {
  int g = blockIdx.x*4 + (threadIdx.x >> 6);
  int lane = threadIdx.x & 63;
  constexpr int E = (n + 63)/64;
  float s[E]; int si[E];
  #pragma unroll
  for (int e = 0; e < E; ++e) {
    int i = e*64 + lane;
    if (i < n) { s[e] = score[(size_t)g*n + i]; si[e] = i; }
    else { s[e] = -INFINITY; si[e] = 1 << 30; }
  }
  for (int kk = 0; kk < k; ++kk) {
    float bs_ = -INFINITY; int bi = 1 << 30;
    #pragma unroll
    for (int e = 0; e < E; ++e)
      if (s[e] > bs_ || (s[e] == bs_ && si[e] < bi)) { bs_ = s[e]; bi = si[e]; }
    for (int off = 32; off; off >>= 1) {
      float os = __shfl_xor(bs_, off);
      int oi = __shfl_xor(bi, off);
      if (os > bs_ || (os == bs_ && oi < bi)) { bs_ = os; bi = oi; }
    }
    if (lane == 0) { idx_out[(size_t)g*k + kk] = bi; tv_out[(size_t)g*k + kk] = tanhf(bs_); }
    #pragma unroll
    for (int e = 0; e < E; ++e) if (si[e] == bi) s[e] = -INFINITY;
  }
}

// ---------------- layer0 selection: recompute x1 rows for top-32, gate, readout, a1 gather ----------------
__global__ void k_sel0(const float* __restrict__ T0, const float* __restrict__ W0,
                       const float* __restrict__ norm0, const float* __restrict__ b0,
                       const int* __restrict__ idx, const float* __restrict__ tv,
                       const float* __restrict__ adj, float* __restrict__ x_sel,
                       float* __restrict__ a1, float* __restrict__ merged) {
  __shared__ float sT[KS0*FF];     // 16 KB
  __shared__ int sidx[KS0]; __shared__ float stv[KS0]; __shared__ float snv[KS0];
  int g = blockIdx.x, t = threadIdx.x;
  if (t < KS0) { sidx[t] = idx[g*KS0 + t]; stv[t] = tv[g*KS0 + t]; }
  __syncthreads();
  if (t < KS0) snv[t] = norm0[g*NN + sidx[t]];
  #pragma unroll
  for (int i = 0; i < 16; ++i) {
    int e = t + i*256, r = e >> 7, c = e & 127;
    sT[e] = T0[((size_t)g*NN + sidx[r])*FF + c];
  }
  __syncthreads();
  float sum[KS0];
  #pragma unroll
  for (int j = 0; j < KS0; ++j) sum[j] = 0.f;
  for (int k = 0; k < FF; k += 4) {
    float4 w;
    w.x = W0[(size_t)(k+0)*DD + t]; w.y = W0[(size_t)(k+1)*DD + t];
    w.z = W0[(size_t)(k+2)*DD + t]; w.w = W0[(size_t)(k+3)*DD + t];
    #pragma unroll
    for (int j = 0; j < KS0; ++j) {
      float4 tv4 = *reinterpret_cast<const float4*>(&sT[j*FF + k]);
      sum[j] += tv4.x*w.x + tv4.y*w.y + tv4.z*w.z + tv4.w*w.w;
    }
  }
  float b = b0[t];
  float s = 0.f, mx = -INFINITY;
  #pragma unroll
  for (int j = 0; j < KS0; ++j) {
    float val = lrelu(snv[j]*sum[j] + b) * stv[j];
    x_sel[((size_t)g*KS0 + j)*DD + t] = val;
    s += val; mx = fmaxf(mx, val);
  }
  merged[(size_t)g*1536 + t] = s;
  merged[(size_t)g*1536 + 256 + t] = mx;
  for (int e = t; e < KS0*KS0; e += 256) {
    int r = e >> 5, c = e & 31;
    a1[(size_t)g*KS0*KS0 + e] = adj[(size_t)g*NN*NN + (size_t)sidx[r]*NN + sidx[c]];
  }
}

// ---------------- gathers + readouts (layers 1/2) ----------------
__global__ void k_gather1(const float* __restrict__ x2, const float* __restrict__ a1,
                          const int* __restrict__ idx, const float* __restrict__ tv,
                          float* __restrict__ x_sel2, float* __restrict__ a2,
                          float* __restrict__ merged) {
  __shared__ int sidx[KS1]; __shared__ float stv[KS1];
  int g = blockIdx.x; int t = threadIdx.x;
  if (t < KS1) { sidx[t] = idx[g*KS1 + t]; stv[t] = tv[g*KS1 + t]; }
  __syncthreads();
  float sum = 0.f, mx = -INFINITY;
  for (int j = 0; j < KS1; ++j) {
    float v = x2[((size_t)g*KS0 + sidx[j])*DD + t] * stv[j];
    x_sel2[((size_t)g*KS1 + j)*DD + t] = v;
    sum += v; mx = fmaxf(mx, v);
  }
  merged[(size_t)g*1536 + 512 + t] = sum;
  merged[(size_t)g*1536 + 768 + t] = mx;
  {
    int r = t >> 4, c = t & 15;
    a2[(size_t)g*KS1*KS1 + t] = a1[(size_t)g*KS0*KS0 + sidx[r]*KS0 + sidx[c]];
  }
}

__global__ void k_gather2(const float* __restrict__ x3, const int* __restrict__ idx,
                          const float* __restrict__ tv, float* __restrict__ merged) {
  __shared__ int sidx[KS2]; __shared__ float stv[KS2];
  int g = blockIdx.x; int t = threadIdx.x;
  if (t < KS2) { sidx[t] = idx[g*KS2 + t]; stv[t] = tv[g*KS2 + t]; }
  __syncthreads();
  float sum = 0.f, mx = -INFINITY;
  for (int j = 0; j < KS2; ++j) {
    float v = x3[((size_t)g*KS1 + sidx[j])*DD + t] * stv[j];
    sum += v; mx = fmaxf(mx, v);
  }
  merged[(size_t)g*1536 + 1024 + t] = sum;
  merged[(size_t)g*1536 + 1280 + t] = mx;
}

// ---------------- dense small spmm: norm from a, T = a @ (x*norm) ----------------
template<int n>
__global__ void k_spmm_dense(const float* __restrict__ a, const float* __restrict__ x,
                             float* __restrict__ normv, float* __restrict__ T) {
  __shared__ float sa[n*n];
  __shared__ float snorm[n];
  __shared__ float sx[n*DD];
  int g = blockIdx.x; int t = threadIdx.x;
  for (int e = t; e < n*n; e += 256) sa[e] = a[(size_t)g*n*n + e];
  __syncthreads();
  if (t < n) {
    float dg = 0.f;
    for (int m = 0; m < n; ++m) dg += sa[t*n + m];
    float nv = rsqrtf(fmaxf(dg, 1.f));
    snorm[t] = nv; normv[g*n + t] = nv;
  }
  __syncthreads();
  for (int e = t; e < n*DD; e += 256) sx[e] = x[(size_t)g*n*DD + e] * snorm[e >> 8];
  __syncthreads();
  float acc[n];
  #pragma unroll
  for (int r = 0; r < n; ++r) acc[r] = 0.f;
  for (int m = 0; m < n; ++m) {
    float xv = sx[m*DD + t];
    #pragma unroll
    for (int r = 0; r < n; ++r) acc[r] += sa[r*n + m]*xv;
  }
  for (int r = 0; r < n; ++r) T[((size_t)g*n + r)*DD + t] = acc[r];
}

// ---------------- final MLP ----------------
__global__ void k_mlp(const float* __restrict__ merged, const float* __restrict__ Wd1,
                      const float* __restrict__ bd1, const float* __restrict__ Wd2,
                      const float* __restrict__ bd2, float* __restrict__ out) {
  __shared__ float sm[1536];
  __shared__ float sh[128];
  int g = blockIdx.x; int t = threadIdx.x;     // 128 threads
  for (int i = t; i < 1536; i += 128) sm[i] = merged[(size_t)g*1536 + i];
  __syncthreads();
  float acc = 0.f;
  for (int k = 0; k < 1536; ++k) acc += sm[k]*Wd1[(size_t)k*128 + t];
  sh[t] = lrelu(acc + bd1[t]);
  __syncthreads();
  if (t < 2) {
    float o = 0.f;
    for (int k = 0; k < 128; ++k) o += sh[k]*Wd2[k*2 + t];
    out[(size_t)g*2 + t] = 1.f/(1.f + expf(-(o + bd2[t])));
  }
}

extern "C" void kernel_launch(void* const* d_in, const int* in_sizes, int n_in,
                              void* d_out, int out_size, void* d_ws, size_t ws_size,
                              hipStream_t stream) {
  const float* feat = (const float*)d_in[0];
  const float* adj  = (const float*)d_in[1];
  const float* W0 = (const float*)d_in[2];  const float* b0  = (const float*)d_in[3];
  const float* Ws0= (const float*)d_in[4];  const float* bs0 = (const float*)d_in[5];
  const float* W1 = (const float*)d_in[6];  const float* b1  = (const float*)d_in[7];
  const float* Ws1= (const float*)d_in[8];  const float* bs1 = (const float*)d_in[9];
  const float* W2 = (const float*)d_in[10]; const float* b2  = (const float*)d_in[11];
  const float* Ws2= (const float*)d_in[12]; const float* bs2 = (const float*)d_in[13];
  const float* Wd1= (const float*)d_in[14]; const float* bd1 = (const float*)d_in[15];
  const float* Wd2= (const float*)d_in[16]; const float* bd2 = (const float*)d_in[17];
  float* out = (float*)d_out;

  char* ws = (char*)d_ws;
  size_t off = 0;
  auto alloc = [&](size_t bytes) -> char* {
    char* p = ws + off; off += (bytes + 255) & ~(size_t)255; return p;
  };
  float* norm0 = (float*)alloc((size_t)GG*NN*4);
  float* hs0   = (float*)alloc((size_t)GG*NN*4);
  float* score0= (float*)alloc((size_t)GG*NN*4);
  int*   idx0  = (int*)  alloc((size_t)GG*KS0*4);
  float* tv0   = (float*)alloc((size_t)GG*KS0*4);
  float* norm1 = (float*)alloc((size_t)GG*KS0*4);
  float* hs1   = (float*)alloc((size_t)GG*KS0*4);
  float* score1= (float*)alloc((size_t)GG*KS0*4);
  int*   idx1  = (int*)  alloc((size_t)GG*KS1*4);
  float* tv1   = (float*)alloc((size_t)GG*KS1*4);
  float* norm2 = (float*)alloc((size_t)GG*KS1*4);
  float* hs2   = (float*)alloc((size_t)GG*KS1*4);
  float* score2= (float*)alloc((size_t)GG*KS1*4);
  int*   idx2  = (int*)  alloc((size_t)GG*KS2*4);
  float* tv2   = (float*)alloc((size_t)GG*KS2*4);
  float* merged= (float*)alloc((size_t)GG*1536*4);
  unsigned short* W0s = (unsigned short*)alloc((size_t)3*FF*DD*2);
  unsigned short* W1s = (unsigned short*)alloc((size_t)3*DD*DD*2);
  unsigned short* W2s = (unsigned short*)alloc((size_t)3*DD*DD*2);
  char* regA = alloc((size_t)GG*NN*FF*4);        // 128 MB: T0, later T1
  char* regB = alloc((size_t)3*GG*FF*NN*2);      // 192 MB: Xt, later layer1+ buffers

  float* T0 = (float*)regA;
  float* T1 = (float*)regA;                 // reuse after k_sel0 consumed T0
  unsigned short* Xt = (unsigned short*)regB;                        // 192 MB (dead after spmm)
  float* x_sel1 = (float*)regB;                                      // 32 MB
  float* a1     = (float*)(regB + (size_t)GG*KS0*DD*4);              //  4 MB
  float* x2     = (float*)((char*)a1     + (size_t)GG*KS0*KS0*4);    // 32 MB
  float* x_sel2 = (float*)((char*)x2     + (size_t)GG*KS0*DD*4);     // 16 MB
  float* a2     = (float*)((char*)x_sel2 + (size_t)GG*KS1*DD*4);     //  1 MB
  float* T2     = (float*)((char*)a2     + (size_t)GG*KS1*KS1*4);    // 16 MB
  float* x3     = (float*)((char*)T2     + (size_t)GG*KS1*DD*4);     // 16 MB

  // ---- weight pre-split (frag-blocked layout) ----
  k_splitW<<<(FF*DD + 255)/256, 256, 0, stream>>>(W0, W0s, FF);
  k_splitW<<<(DD*DD + 255)/256, 256, 0, stream>>>(W1, W1s, DD);
  k_splitW<<<(DD*DD + 255)/256, 256, 0, stream>>>(W2, W2s, DD);

  // ---- layer 0 (all streaming, no CSR) ----
  k_norm<<<GG*NN/4, 256, 0, stream>>>(adj, norm0);
  k_xsplit<<<GG, 256, 0, stream>>>(feat, norm0, Xt);
  k_spmm_mfma<<<GG, 256, 0, stream>>>(adj, Xt, T0);
  k_gemm_mfma<FF, false><<<GG*NN/32, 64, 0, stream>>>(T0, W0s, norm0, b0, Ws0, nullptr, hs0);
  k_score0<<<GG, 256, 0, stream>>>(adj, hs0, norm0, bs0, score0);
  k_topk<NN, KS0><<<GG/4, 256, 0, stream>>>(score0, idx0, tv0);
  k_sel0<<<GG, 256, 0, stream>>>(T0, W0, norm0, b0, idx0, tv0, adj, x_sel1, a1, merged);

  // ---- layer 1 ----
  k_spmm_dense<KS0><<<GG, 256, 0, stream>>>(a1, x_sel1, norm1, T1);
  k_gemm_mfma<DD, true><<<GG*KS0/32, 64, 0, stream>>>(T1, W1s, norm1, b1, Ws1, x2, hs1);
  k_score_dense<KS0><<<(GG*KS0 + 255)/256, 256, 0, stream>>>(a1, hs1, norm1, bs1, score1);
  k_topk<KS0, KS1><<<GG/4, 256, 0, stream>>>(score1, idx1, tv1);
  k_gather1<<<GG, 256, 0, stream>>>(x2, a1, idx1, tv1, x_sel2, a2, merged);

  // ---- layer 2 ----
  k_spmm_dense<KS1><<<GG, 256, 0, stream>>>(a2, x_sel2, norm2, T2);
  k_gemm_mfma<DD, true><<<GG*KS1/32, 64, 0, stream>>>(T2, W2s, norm2, b2, Ws2, x3, hs2);
  k_score_dense<KS1><<<(GG*KS1 + 255)/256, 256, 0, stream>>>(a2, hs2, norm2, bs2, score2);
  k_topk<KS1, KS2><<<GG/4, 256, 0, stream>>>(score2, idx2, tv2);
  k_gather2<<<GG, 256, 0, stream>>>(x3, idx2, tv2, merged);

  // ---- MLP head ----
  k_mlp<<<GG, 128, 0, stream>>>(merged, Wd1, bd1, Wd2, bd2, out);

  (void)in_sizes; (void)n_in; (void)out_size; (void)ws_size;
}

// Round 6
// 1182.752 us; speedup vs baseline: 1.3252x; 1.1053x over previous
//
#include <hip/hip_runtime.h>
#include <math.h>

constexpr int GG  = 1024;   // graphs
constexpr int NN  = 256;    // nodes layer0
constexpr int FF  = 128;    // input feat
constexpr int DD  = 256;    // hidden
constexpr int KS0 = 32, KS1 = 16, KS2 = 8;

__device__ __forceinline__ float lrelu(float x){ return x >= 0.f ? x : 0.01f*x; }

// bf16 helpers
__device__ __forceinline__ unsigned short f2bf(float f) {
  unsigned u = __float_as_uint(f);
  unsigned r = (u + 0x7FFFu + ((u >> 16) & 1u)) >> 16;
  return (unsigned short)r;
}
__device__ __forceinline__ float bf2f(unsigned short h) {
  return __uint_as_float(((unsigned)h) << 16);
}

typedef __attribute__((ext_vector_type(8)))  __bf16 bf16x8;
typedef __attribute__((ext_vector_type(16))) float  f32x16;

union Frag8 { unsigned short us[8]; unsigned long long u64[2]; bf16x8 v; };

// ---------------- pre-split weights into 3 bf16 planes, frag-blocked kti-major ----------------
// e = (((kti*2 + s)*8 + nt)*64 + lane)*8 + j ; lane=(n&31)+32*((k>>3)&1) ;
// k = kti*32 + s*16 + ((lane>>5)<<3) + j ; n = nt*32 + (lane&31)
__global__ void k_splitW(const float* __restrict__ W, unsigned short* __restrict__ out, int K) {
  int e = blockIdx.x*256 + threadIdx.x;
  if (e >= DD*K) return;
  int j    = e & 7;
  int lane = (e >> 3) & 63;
  int nt   = (e >> 9) & 7;
  int s    = (e >> 12) & 1;
  int kti  = e >> 13;
  int n = nt*32 + (lane & 31);
  int k = kti*32 + s*16 + ((lane >> 5) << 3) + j;
  float x = W[(size_t)k*DD + n];
  unsigned short h1 = f2bf(x);  float r1 = x - bf2f(h1);
  unsigned short h2 = f2bf(r1); float r2 = r1 - bf2f(h2);
  unsigned short h3 = f2bf(r2);
  out[e] = h1; out[DD*K + e] = h2; out[2*DD*K + e] = h3;
}

// ---------------- mask + norm: wave per row; 4 x ballot -> 256-bit row mask; popcount degree ----------------
__global__ void k_maskrow(const float* __restrict__ adj, float* __restrict__ norm0,
                          unsigned long long* __restrict__ mask) {
  int row = blockIdx.x*4 + (threadIdx.x >> 6);
  int lane = threadIdx.x & 63;
  const float* ar = adj + (size_t)row*NN;
  float f0 = ar[lane], f1 = ar[64 + lane], f2 = ar[128 + lane], f3 = ar[192 + lane];
  unsigned long long m0 = __ballot(f0 > 0.5f);
  unsigned long long m1 = __ballot(f1 > 0.5f);
  unsigned long long m2 = __ballot(f2 > 0.5f);
  unsigned long long m3 = __ballot(f3 > 0.5f);
  if (lane < 4) {
    unsigned long long mm = lane == 0 ? m0 : lane == 1 ? m1 : lane == 2 ? m2 : m3;
    mask[(size_t)row*4 + lane] = mm;
  }
  if (lane == 0) {
    int cnt = __popcll(m0) + __popcll(m1) + __popcll(m2) + __popcll(m3);
    norm0[row] = rsqrtf(fmaxf((float)cnt, 1.0f));
  }
}

// ---------------- Xt[sp][g][n][k] = split_sp(X[g][k][n] * norm[k]), k-contiguous ----------------
__global__ void k_xsplit(const float* __restrict__ feat, const float* __restrict__ norm0,
                         unsigned short* __restrict__ Xt) {
  __shared__ unsigned short ls[3*128*32];   // 24 KB
  __shared__ float snorm[NN];
  int g = blockIdx.x, t = threadIdx.x;
  snorm[t] = norm0[g*NN + t];
  __syncthreads();
  const float* Xg = feat + (size_t)g*NN*FF;
  for (int chunk = 0; chunk < 8; ++chunk) {
    #pragma unroll
    for (int i = 0; i < 16; ++i) {
      int e = t + i*256;
      int m = chunk*32 + (e >> 7), c = e & 127;
      float x = Xg[(size_t)m*FF + c] * snorm[m];
      unsigned short h1 = f2bf(x);  float r1 = x - bf2f(h1);
      unsigned short h2 = f2bf(r1); float r2 = r1 - bf2f(h2);
      unsigned short h3 = f2bf(r2);
      int mm = m & 31;
      ls[(0*128 + c)*32 + mm] = h1;
      ls[(1*128 + c)*32 + mm] = h2;
      ls[(2*128 + c)*32 + mm] = h3;
    }
    __syncthreads();
    int n = t >> 1, half = t & 1;
    #pragma unroll
    for (int sp = 0; sp < 3; ++sp) {
      const ulonglong2* src = reinterpret_cast<const ulonglong2*>(&ls[((sp*128 + n)*32) + half*16]);
      size_t dst = (((size_t)sp*GG + g)*128 + n)*256 + chunk*32 + half*16;
      ulonglong2* d = reinterpret_cast<ulonglong2*>(Xt + dst);
      d[0] = src[0];
      d[1] = src[1];
    }
    __syncthreads();
  }
}

// ---------------- T0 = A @ Xn via bf16 MFMA: LDS-free, barrier-free ----------------
__global__ __launch_bounds__(256, 2) void k_spmm_mfma(
    const float* __restrict__ adj, const unsigned short* __restrict__ Xt,
    float* __restrict__ T0) {
  int g = blockIdx.x;
  int t = threadIdx.x;
  int lane = t & 63, wave = t >> 6;
  int lm = lane & 31, lh = lane >> 5;

  const float* Ag = adj + (size_t)g*NN*NN;

  f32x16 acc[2][4];
  #pragma unroll
  for (int i = 0; i < 2; ++i)
    #pragma unroll
    for (int j = 0; j < 4; ++j) acc[i][j] = (f32x16)0.0f;

  for (int kt = 0; kt < NN; kt += 32) {
    Frag8 afr[2][2];
    #pragma unroll
    for (int mt = 0; mt < 2; ++mt)
      #pragma unroll
      for (int s = 0; s < 2; ++s) {
        const float* ap = Ag + (size_t)(wave*64 + mt*32 + lm)*NN + kt + s*16 + lh*8;
        float4 a0 = *reinterpret_cast<const float4*>(ap);
        float4 a1 = *reinterpret_cast<const float4*>(ap + 4);
        afr[mt][s].us[0] = f2bf(a0.x); afr[mt][s].us[1] = f2bf(a0.y);
        afr[mt][s].us[2] = f2bf(a0.z); afr[mt][s].us[3] = f2bf(a0.w);
        afr[mt][s].us[4] = f2bf(a1.x); afr[mt][s].us[5] = f2bf(a1.y);
        afr[mt][s].us[6] = f2bf(a1.z); afr[mt][s].us[7] = f2bf(a1.w);
      }

    #pragma unroll
    for (int s = 0; s < 2; ++s)
      #pragma unroll
      for (int nt = 0; nt < 4; ++nt) {
        size_t bbase = ((size_t)g*128 + nt*32 + lm)*256 + kt + s*16 + lh*8;
        Frag8 b0_, b1_, b2_;
        b0_.v = *reinterpret_cast<const bf16x8*>(Xt + bbase);
        b1_.v = *reinterpret_cast<const bf16x8*>(Xt + (size_t)GG*128*256 + bbase);
        b2_.v = *reinterpret_cast<const bf16x8*>(Xt + (size_t)2*GG*128*256 + bbase);
        #pragma unroll
        for (int mt = 0; mt < 2; ++mt) {
          acc[mt][nt] = __builtin_amdgcn_mfma_f32_32x32x16_bf16(afr[mt][s].v, b0_.v, acc[mt][nt], 0,0,0);
          acc[mt][nt] = __builtin_amdgcn_mfma_f32_32x32x16_bf16(afr[mt][s].v, b1_.v, acc[mt][nt], 0,0,0);
          acc[mt][nt] = __builtin_amdgcn_mfma_f32_32x32x16_bf16(afr[mt][s].v, b2_.v, acc[mt][nt], 0,0,0);
        }
      }
  }

  #pragma unroll
  for (int mt = 0; mt < 2; ++mt)
    #pragma unroll
    for (int nt = 0; nt < 4; ++nt)
      #pragma unroll
      for (int r = 0; r < 16; ++r) {
        int row = wave*64 + mt*32 + (r & 3) + 8*(r >> 2) + 4*lh;
        int col = nt*32 + lm;
        T0[((size_t)g*NN + row)*FF + col] = acc[mt][nt][r];
      }
}

// ---------------- layer0 GEMM: 4-wave blocks, B staged in LDS (shared by waves) ----------------
__global__ __launch_bounds__(256, 2) void k_gemm0(
    const float* __restrict__ Tmat, const unsigned short* __restrict__ Wk,
    const float* __restrict__ normv, const float* __restrict__ bias,
    const float* __restrict__ Ws, float* __restrict__ hs) {
  __shared__ unsigned short bsh[3*8192];   // 48 KB: one k-tile of all 3 planes
  int t = threadIdx.x;
  int lane = t & 63, wave = t >> 6;
  int lm = lane & 31, lh = lane >> 5;
  int rowbase = blockIdx.x*128 + wave*32;

  f32x16 acc[8];
  #pragma unroll
  for (int nt = 0; nt < 8; ++nt) acc[nt] = (f32x16)0.0f;

  for (int kti = 0; kti < 4; ++kti) {
    int kt = kti*32;
    // A fragments (fp32, rows exclusive to this wave)
    float4 af[2][2];
    #pragma unroll
    for (int s = 0; s < 2; ++s) {
      const float* ap = Tmat + (size_t)(rowbase + lm)*FF + kt + s*16 + lh*8;
      af[s][0] = *reinterpret_cast<const float4*>(ap);
      af[s][1] = *reinterpret_cast<const float4*>(ap + 4);
    }
    // stage B k-tile: 48KB, 16B per thread per iter
    __syncthreads();
    #pragma unroll
    for (int sp = 0; sp < 3; ++sp)
      #pragma unroll
      for (int r = 0; r < 4; ++r) {
        const uint4* src = reinterpret_cast<const uint4*>(
            Wk + (size_t)sp*DD*FF + (size_t)kti*8192 + r*2048 + t*8);
        *reinterpret_cast<uint4*>(bsh + sp*8192 + r*2048 + t*8) = *src;
      }
    __syncthreads();
    // split A in-register
    Frag8 afr[2][3];
    #pragma unroll
    for (int s = 0; s < 2; ++s) {
      const float* fv = &af[s][0].x;
      #pragma unroll
      for (int j = 0; j < 8; ++j) {
        float x = fv[j];
        unsigned short h1 = f2bf(x);  float r1 = x - bf2f(h1);
        unsigned short h2 = f2bf(r1); float r2 = r1 - bf2f(h2);
        afr[s][0].us[j] = h1; afr[s][1].us[j] = h2; afr[s][2].us[j] = f2bf(r2);
      }
    }
    #pragma unroll
    for (int s = 0; s < 2; ++s)
      #pragma unroll
      for (int nt = 0; nt < 8; ++nt) {
        const unsigned short* bp = bsh + ((s*8 + nt)*64 + lane)*8;
        Frag8 b0_, b1_, b2_;
        b0_.v = *reinterpret_cast<const bf16x8*>(bp);
        b1_.v = *reinterpret_cast<const bf16x8*>(bp + 8192);
        b2_.v = *reinterpret_cast<const bf16x8*>(bp + 16384);
        acc[nt] = __builtin_amdgcn_mfma_f32_32x32x16_bf16(afr[s][0].v, b0_.v, acc[nt], 0,0,0);
        acc[nt] = __builtin_amdgcn_mfma_f32_32x32x16_bf16(afr[s][0].v, b1_.v, acc[nt], 0,0,0);
        acc[nt] = __builtin_amdgcn_mfma_f32_32x32x16_bf16(afr[s][1].v, b0_.v, acc[nt], 0,0,0);
        acc[nt] = __builtin_amdgcn_mfma_f32_32x32x16_bf16(afr[s][0].v, b2_.v, acc[nt], 0,0,0);
        acc[nt] = __builtin_amdgcn_mfma_f32_32x32x16_bf16(afr[s][2].v, b0_.v, acc[nt], 0,0,0);
        acc[nt] = __builtin_amdgcn_mfma_f32_32x32x16_bf16(afr[s][1].v, b1_.v, acc[nt], 0,0,0);
      }
  }

  float bcol[8], wcol[8];
  #pragma unroll
  for (int nt = 0; nt < 8; ++nt) { int col = nt*32 + lm; bcol[nt] = bias[col]; wcol[nt] = Ws[col]; }
  float hsum[16];
  #pragma unroll
  for (int r = 0; r < 16; ++r) {
    int row = rowbase + (r & 3) + 8*(r >> 2) + 4*lh;
    float nv = normv[row];
    float hp = 0.f;
    #pragma unroll
    for (int nt = 0; nt < 8; ++nt) hp += lrelu(nv*acc[nt][r] + bcol[nt])*wcol[nt];
    hsum[r] = hp;
  }
  #pragma unroll
  for (int off = 1; off <= 16; off <<= 1)
    #pragma unroll
    for (int r = 0; r < 16; ++r) hsum[r] += __shfl_xor(hsum[r], off);
  if (lm == 0)
    #pragma unroll
    for (int r = 0; r < 16; ++r) {
      int row = rowbase + (r & 3) + 8*(r >> 2) + 4*lh;
      hs[row] = normv[row]*hsum[r];
    }
}

// ---------------- MFMA GEMM (layers 1/2), LDS-free: one wave = 32 rows x 256 cols ----------------
template<int K, bool WRITE_X>
__global__ __launch_bounds__(64, 2) void k_gemm_mfma(
    const float* __restrict__ Tmat, const unsigned short* __restrict__ Wk,
    const float* __restrict__ normv, const float* __restrict__ bias,
    const float* __restrict__ Ws, float* __restrict__ xout, float* __restrict__ hs) {
  int lane = threadIdx.x;
  int lm = lane & 31, lh = lane >> 5;
  int rowbase = blockIdx.x * 32;

  f32x16 acc[8];
  #pragma unroll
  for (int nt = 0; nt < 8; ++nt) acc[nt] = (f32x16)0.0f;

  for (int kt = 0; kt < K; kt += 32) {
    float4 af[2][2];
    #pragma unroll
    for (int s = 0; s < 2; ++s) {
      const float* ap = Tmat + (size_t)(rowbase + lm)*K + kt + s*16 + lh*8;
      af[s][0] = *reinterpret_cast<const float4*>(ap);
      af[s][1] = *reinterpret_cast<const float4*>(ap + 4);
    }
    Frag8 afr[2][3];
    #pragma unroll
    for (int s = 0; s < 2; ++s) {
      const float* fv = &af[s][0].x;
      #pragma unroll
      for (int j = 0; j < 8; ++j) {
        float x = fv[j];
        unsigned short h1 = f2bf(x);  float r1 = x - bf2f(h1);
        unsigned short h2 = f2bf(r1); float r2 = r1 - bf2f(h2);
        afr[s][0].us[j] = h1; afr[s][1].us[j] = h2; afr[s][2].us[j] = f2bf(r2);
      }
    }
    #pragma unroll
    for (int s = 0; s < 2; ++s)
      #pragma unroll
      for (int nt = 0; nt < 8; ++nt) {
        size_t boff = ((((size_t)(kt >> 5)*2 + s)*8 + nt)*64 + lane)*8;
        Frag8 b0_, b1_, b2_;
        b0_.v = *reinterpret_cast<const bf16x8*>(Wk + boff);
        b1_.v = *reinterpret_cast<const bf16x8*>(Wk + (size_t)DD*K + boff);
        b2_.v = *reinterpret_cast<const bf16x8*>(Wk + (size_t)2*DD*K + boff);
        acc[nt] = __builtin_amdgcn_mfma_f32_32x32x16_bf16(afr[s][0].v, b0_.v, acc[nt], 0,0,0);
        acc[nt] = __builtin_amdgcn_mfma_f32_32x32x16_bf16(afr[s][0].v, b1_.v, acc[nt], 0,0,0);
        acc[nt] = __builtin_amdgcn_mfma_f32_32x32x16_bf16(afr[s][1].v, b0_.v, acc[nt], 0,0,0);
        acc[nt] = __builtin_amdgcn_mfma_f32_32x32x16_bf16(afr[s][0].v, b2_.v, acc[nt], 0,0,0);
        acc[nt] = __builtin_amdgcn_mfma_f32_32x32x16_bf16(afr[s][2].v, b0_.v, acc[nt], 0,0,0);
        acc[nt] = __builtin_amdgcn_mfma_f32_32x32x16_bf16(afr[s][1].v, b1_.v, acc[nt], 0,0,0);
      }
  }

  float bcol[8], wcol[8];
  #pragma unroll
  for (int nt = 0; nt < 8; ++nt) { int col = nt*32 + lm; bcol[nt] = bias[col]; wcol[nt] = Ws[col]; }
  float hsum[16];
  #pragma unroll
  for (int r = 0; r < 16; ++r) {
    int row = rowbase + (r & 3) + 8*(r >> 2) + 4*lh;
    float nv = normv[row];
    float hp = 0.f;
    #pragma unroll
    for (int nt = 0; nt < 8; ++nt) {
      float val = lrelu(nv*acc[nt][r] + bcol[nt]);
      if (WRITE_X) xout[(size_t)row*DD + nt*32 + lm] = val;
      hp += val*wcol[nt];
    }
    hsum[r] = hp;
  }
  #pragma unroll
  for (int off = 1; off <= 16; off <<= 1)
    #pragma unroll
    for (int r = 0; r < 16; ++r) hsum[r] += __shfl_xor(hsum[r], off);
  if (lm == 0)
    #pragma unroll
    for (int r = 0; r < 16; ++r) {
      int row = rowbase + (r & 3) + 8*(r >> 2) + 4*lh;
      hs[row] = normv[row]*hsum[r];
    }
}

// ---------------- layer0: score via bitmask + fused top-k ----------------
__global__ void k_score_topk0(const unsigned long long* __restrict__ mask,
                              const float* __restrict__ hs, const float* __restrict__ norm0,
                              const float* __restrict__ bs,
                              int* __restrict__ idx_out, float* __restrict__ tv_out) {
  __shared__ float sh[NN];
  __shared__ float ssc[NN];
  int g = blockIdx.x, t = threadIdx.x;
  sh[t] = hs[g*NN + t];
  __syncthreads();
  const unsigned long long* mr = mask + ((size_t)g*NN + t)*4;
  float s = 0.f;
  #pragma unroll
  for (int w = 0; w < 4; ++w) {
    unsigned long long m = mr[w];
    const float* base = sh + w*64;
    while (m) {
      int c = __builtin_ctzll(m);
      s += base[c];
      m &= m - 1;
    }
  }
  ssc[t] = norm0[g*NN + t]*s + bs[0];
  __syncthreads();
  if (t < 64) {
    float sv[4]; int si[4];
    #pragma unroll
    for (int e = 0; e < 4; ++e) { sv[e] = ssc[e*64 + t]; si[e] = e*64 + t; }
    for (int kk = 0; kk < KS0; ++kk) {
      float bs_ = -INFINITY; int bi = 1 << 30;
      #pragma unroll
      for (int e = 0; e < 4; ++e)
        if (sv[e] > bs_ || (sv[e] == bs_ && si[e] < bi)) { bs_ = sv[e]; bi = si[e]; }
      for (int off = 32; off; off >>= 1) {
        float os = __shfl_xor(bs_, off);
        int oi = __shfl_xor(bi, off);
        if (os > bs_ || (os == bs_ && oi < bi)) { bs_ = os; bi = oi; }
      }
      if (t == 0) { idx_out[g*KS0 + kk] = bi; tv_out[g*KS0 + kk] = tanhf(bs_); }
      #pragma unroll
      for (int e = 0; e < 4; ++e) if (si[e] == bi) sv[e] = -INFINITY;
    }
  }
}

// ---------------- layer0 selection: recompute x1 rows for top-32, gate, readout, a1 gather ----------------
__global__ void k_sel0(const float* __restrict__ T0, const float* __restrict__ W0,
                       const float* __restrict__ norm0, const float* __restrict__ b0,
                       const int* __restrict__ idx, const float* __restrict__ tv,
                       const float* __restrict__ adj, float* __restrict__ x_sel,
                       float* __restrict__ a1, float* __restrict__ merged) {
  __shared__ float sT[KS0*FF];     // 16 KB
  __shared__ int sidx[KS0]; __shared__ float stv[KS0]; __shared__ float snv[KS0];
  int g = blockIdx.x, t = threadIdx.x;
  if (t < KS0) { sidx[t] = idx[g*KS0 + t]; stv[t] = tv[g*KS0 + t]; }
  __syncthreads();
  if (t < KS0) snv[t] = norm0[g*NN + sidx[t]];
  #pragma unroll
  for (int i = 0; i < 16; ++i) {
    int e = t + i*256, r = e >> 7, c = e & 127;
    sT[e] = T0[((size_t)g*NN + sidx[r])*FF + c];
  }
  __syncthreads();
  float sum[KS0];
  #pragma unroll
  for (int j = 0; j < KS0; ++j) sum[j] = 0.f;
  for (int k = 0; k < FF; k += 4) {
    float4 w;
    w.x = W0[(size_t)(k+0)*DD + t]; w.y = W0[(size_t)(k+1)*DD + t];
    w.z = W0[(size_t)(k+2)*DD + t]; w.w = W0[(size_t)(k+3)*DD + t];
    #pragma unroll
    for (int j = 0; j < KS0; ++j) {
      float4 tv4 = *reinterpret_cast<const float4*>(&sT[j*FF + k]);
      sum[j] += tv4.x*w.x + tv4.y*w.y + tv4.z*w.z + tv4.w*w.w;
    }
  }
  float b = b0[t];
  float s = 0.f, mx = -INFINITY;
  #pragma unroll
  for (int j = 0; j < KS0; ++j) {
    float val = lrelu(snv[j]*sum[j] + b) * stv[j];
    x_sel[((size_t)g*KS0 + j)*DD + t] = val;
    s += val; mx = fmaxf(mx, val);
  }
  merged[(size_t)g*1536 + t] = s;
  merged[(size_t)g*1536 + 256 + t] = mx;
  for (int e = t; e < KS0*KS0; e += 256) {
    int r = e >> 5, c = e & 31;
    a1[(size_t)g*KS0*KS0 + e] = adj[(size_t)g*NN*NN + (size_t)sidx[r]*NN + sidx[c]];
  }
}

// ---------------- fused pool (layers 1/2): score + top-k + gather + readout ----------------
template<int n, int k, bool LAST>
__global__ void k_pool(const float* __restrict__ x, const float* __restrict__ a,
                       const float* __restrict__ hs, const float* __restrict__ normv,
                       const float* __restrict__ bs, float* __restrict__ x_sel,
                       float* __restrict__ a_out, float* __restrict__ merged, int moff) {
  __shared__ float sa[n*n];
  __shared__ float shs[n];
  __shared__ float ssc[n];
  __shared__ int sidx[k]; __shared__ float stv[k];
  int g = blockIdx.x, t = threadIdx.x;
  for (int e = t; e < n*n; e += 256) sa[e] = a[(size_t)g*n*n + e];
  if (t < n) shs[t] = hs[g*n + t];
  __syncthreads();
  if (t < n) {
    float s = 0.f;
    #pragma unroll
    for (int m = 0; m < n; ++m) s += sa[t*n + m]*shs[m];
    ssc[t] = normv[g*n + t]*s + bs[0];
  }
  __syncthreads();
  if (t < 64) {
    float sc = (t < n) ? ssc[t] : -INFINITY;
    int si = (t < n) ? t : (1 << 30);
    for (int kk = 0; kk < k; ++kk) {
      float bs_ = sc; int bi = si;
      for (int off = 32; off; off >>= 1) {
        float os = __shfl_xor(bs_, off);
        int oi = __shfl_xor(bi, off);
        if (os > bs_ || (os == bs_ && oi < bi)) { bs_ = os; bi = oi; }
      }
      if (t == 0) { sidx[kk] = bi; stv[kk] = tanhf(bs_); }
      if (si == bi) sc = -INFINITY;
    }
  }
  __syncthreads();
  float sum = 0.f, mx = -INFINITY;
  #pragma unroll
  for (int j = 0; j < k; ++j) {
    float v = x[((size_t)g*n + sidx[j])*DD + t] * stv[j];
    if (!LAST) x_sel[((size_t)g*k + j)*DD + t] = v;
    sum += v; mx = fmaxf(mx, v);
  }
  merged[(size_t)g*1536 + moff + t] = sum;
  merged[(size_t)g*1536 + moff + 256 + t] = mx;
  if (!LAST && t < k*k) {
    int r = t / k, c = t - r*k;
    a_out[(size_t)g*k*k + t] = sa[sidx[r]*n + sidx[c]];
  }
}

// ---------------- dense small spmm: norm from a, T = a @ (x*norm) ----------------
template<int n>
__global__ void k_spmm_dense(const float* __restrict__ a, const float* __restrict__ x,
                             float* __restrict__ normv, float* __restrict__ T) {
  __shared__ float sa[n*n];
  __shared__ float snorm[n];
  __shared__ float sx[n*DD];
  int g = blockIdx.x; int t = threadIdx.x;
  for (int e = t; e < n*n; e += 256) sa[e] = a[(size_t)g*n*n + e];
  __syncthreads();
  if (t < n) {
    float dg = 0.f;
    for (int m = 0; m < n; ++m) dg += sa[t*n + m];
    float nv = rsqrtf(fmaxf(dg, 1.f));
    snorm[t] = nv; normv[g*n + t] = nv;
  }
  __syncthreads();
  for (int e = t; e < n*DD; e += 256) sx[e] = x[(size_t)g*n*DD + e] * snorm[e >> 8];
  __syncthreads();
  float acc[n];
  #pragma unroll
  for (int r = 0; r < n; ++r) acc[r] = 0.f;
  for (int m = 0; m < n; ++m) {
    float xv = sx[m*DD + t];
    #pragma unroll
    for (int r = 0; r < n; ++r) acc[r] += sa[r*n + m]*xv;
  }
  for (int r = 0; r < n; ++r) T[((size_t)g*n + r)*DD + t] = acc[r];
}

// ---------------- final MLP: 4 graphs per block for Wd1 reuse ----------------
__global__ void k_mlp(const float* __restrict__ merged, const float* __restrict__ Wd1,
                      const float* __restrict__ bd1, const float* __restrict__ Wd2,
                      const float* __restrict__ bd2, float* __restrict__ out) {
  __shared__ float sm[4*1536];
  __shared__ float sh[4][128];
  int g0 = blockIdx.x*4; int t = threadIdx.x;     // 128 threads
  for (int i = t; i < 4*1536; i += 128) sm[i] = merged[(size_t)g0*1536 + i];
  __syncthreads();
  float a0 = 0.f, a1 = 0.f, a2 = 0.f, a3 = 0.f;
  for (int kk = 0; kk < 1536; ++kk) {
    float w = Wd1[(size_t)kk*128 + t];
    a0 += sm[kk]*w; a1 += sm[1536 + kk]*w; a2 += sm[3072 + kk]*w; a3 += sm[4608 + kk]*w;
  }
  float b = bd1[t];
  sh[0][t] = lrelu(a0 + b); sh[1][t] = lrelu(a1 + b);
  sh[2][t] = lrelu(a2 + b); sh[3][t] = lrelu(a3 + b);
  __syncthreads();
  if (t < 8) {
    int gi = t >> 1, c = t & 1;
    float o = 0.f;
    for (int kk = 0; kk < 128; ++kk) o += sh[gi][kk]*Wd2[kk*2 + c];
    out[(size_t)(g0 + gi)*2 + c] = 1.f/(1.f + expf(-(o + bd2[c])));
  }
}

extern "C" void kernel_launch(void* const* d_in, const int* in_sizes, int n_in,
                              void* d_out, int out_size, void* d_ws, size_t ws_size,
                              hipStream_t stream) {
  const float* feat = (const float*)d_in[0];
  const float* adj  = (const float*)d_in[1];
  const float* W0 = (const float*)d_in[2];  const float* b0  = (const float*)d_in[3];
  const float* Ws0= (const float*)d_in[4];  const float* bs0 = (const float*)d_in[5];
  const float* W1 = (const float*)d_in[6];  const float* b1  = (const float*)d_in[7];
  const float* Ws1= (const float*)d_in[8];  const float* bs1 = (const float*)d_in[9];
  const float* W2 = (const float*)d_in[10]; const float* b2  = (const float*)d_in[11];
  const float* Ws2= (const float*)d_in[12]; const float* bs2 = (const float*)d_in[13];
  const float* Wd1= (const float*)d_in[14]; const float* bd1 = (const float*)d_in[15];
  const float* Wd2= (const float*)d_in[16]; const float* bd2 = (const float*)d_in[17];
  float* out = (float*)d_out;

  char* ws = (char*)d_ws;
  size_t off = 0;
  auto alloc = [&](size_t bytes) -> char* {
    char* p = ws + off; off += (bytes + 255) & ~(size_t)255; return p;
  };
  float* norm0 = (float*)alloc((size_t)GG*NN*4);
  unsigned long long* mask0 = (unsigned long long*)alloc((size_t)GG*NN*4*8);
  float* hs0   = (float*)alloc((size_t)GG*NN*4);
  int*   idx0  = (int*)  alloc((size_t)GG*KS0*4);
  float* tv0   = (float*)alloc((size_t)GG*KS0*4);
  float* norm1 = (float*)alloc((size_t)GG*KS0*4);
  float* hs1   = (float*)alloc((size_t)GG*KS0*4);
  float* norm2 = (float*)alloc((size_t)GG*KS1*4);
  float* hs2   = (float*)alloc((size_t)GG*KS1*4);
  float* merged= (float*)alloc((size_t)GG*1536*4);
  unsigned short* W0s = (unsigned short*)alloc((size_t)3*FF*DD*2);
  unsigned short* W1s = (unsigned short*)alloc((size_t)3*DD*DD*2);
  unsigned short* W2s = (unsigned short*)alloc((size_t)3*DD*DD*2);
  char* regA = alloc((size_t)GG*NN*FF*4);        // 128 MB: T0, later T1
  char* regB = alloc((size_t)3*GG*FF*NN*2);      // 192 MB: Xt, later layer1+ buffers

  float* T0 = (float*)regA;
  float* T1 = (float*)regA;                 // reuse after k_sel0 consumed T0
  unsigned short* Xt = (unsigned short*)regB;                        // dead after spmm
  float* x_sel1 = (float*)regB;                                      // 32 MB
  float* a1     = (float*)(regB + (size_t)GG*KS0*DD*4);              //  4 MB
  float* x2     = (float*)((char*)a1     + (size_t)GG*KS0*KS0*4);    // 32 MB
  float* x_sel2 = (float*)((char*)x2     + (size_t)GG*KS0*DD*4);     // 16 MB
  float* a2     = (float*)((char*)x_sel2 + (size_t)GG*KS1*DD*4);     //  1 MB
  float* T2     = (float*)((char*)a2     + (size_t)GG*KS1*KS1*4);    // 16 MB
  float* x3     = (float*)((char*)T2     + (size_t)GG*KS1*DD*4);     // 16 MB

  // ---- weight pre-split (frag-blocked kti-major layout) ----
  k_splitW<<<(FF*DD + 255)/256, 256, 0, stream>>>(W0, W0s, FF);
  k_splitW<<<(DD*DD + 255)/256, 256, 0, stream>>>(W1, W1s, DD);
  k_splitW<<<(DD*DD + 255)/256, 256, 0, stream>>>(W2, W2s, DD);

  // ---- layer 0 ----
  k_maskrow<<<GG*NN/4, 256, 0, stream>>>(adj, norm0, mask0);
  k_xsplit<<<GG, 256, 0, stream>>>(feat, norm0, Xt);
  k_spmm_mfma<<<GG, 256, 0, stream>>>(adj, Xt, T0);
  k_gemm0<<<GG*NN/128, 256, 0, stream>>>(T0, W0s, norm0, b0, Ws0, hs0);
  k_score_topk0<<<GG, 256, 0, stream>>>(mask0, hs0, norm0, bs0, idx0, tv0);
  k_sel0<<<GG, 256, 0, stream>>>(T0, W0, norm0, b0, idx0, tv0, adj, x_sel1, a1, merged);

  // ---- layer 1 ----
  k_spmm_dense<KS0><<<GG, 256, 0, stream>>>(a1, x_sel1, norm1, T1);
  k_gemm_mfma<DD, true><<<GG*KS0/32, 64, 0, stream>>>(T1, W1s, norm1, b1, Ws1, x2, hs1);
  k_pool<KS0, KS1, false><<<GG, 256, 0, stream>>>(x2, a1, hs1, norm1, bs1, x_sel2, a2, merged, 512);

  // ---- layer 2 ----
  k_spmm_dense<KS1><<<GG, 256, 0, stream>>>(a2, x_sel2, norm2, T2);
  k_gemm_mfma<DD, true><<<GG*KS1/32, 64, 0, stream>>>(T2, W2s, norm2, b2, Ws2, x3, hs2);
  k_pool<KS1, KS2, true><<<GG, 256, 0, stream>>>(x3, a2, hs2, norm2, bs2, nullptr, nullptr, merged, 1024);

  // ---- MLP head ----
  k_mlp<<<GG/4, 128, 0, stream>>>(merged, Wd1, bd1, Wd2, bd2, out);

  (void)in_sizes; (void)n_in; (void)out_size; (void)ws_size;
}

// Round 7
// 1025.615 us; speedup vs baseline: 1.5282x; 1.1532x over previous
//
#include <hip/hip_runtime.h>
#include <math.h>

constexpr int GG  = 1024;   // graphs
constexpr int NN  = 256;    // nodes layer0
constexpr int FF  = 128;    // input feat
constexpr int DD  = 256;    // hidden
constexpr int KS0 = 32, KS1 = 16, KS2 = 8;

__device__ __forceinline__ float lrelu(float x){ return x >= 0.f ? x : 0.01f*x; }

// bf16 helpers
__device__ __forceinline__ unsigned short f2bf(float f) {
  unsigned u = __float_as_uint(f);
  unsigned r = (u + 0x7FFFu + ((u >> 16) & 1u)) >> 16;
  return (unsigned short)r;
}
__device__ __forceinline__ float bf2f(unsigned short h) {
  return __uint_as_float(((unsigned)h) << 16);
}

typedef __attribute__((ext_vector_type(8)))  __bf16 bf16x8;
typedef __attribute__((ext_vector_type(16))) float  f32x16;

union Frag8 { unsigned short us[8]; unsigned long long u64[2]; bf16x8 v; };

// ---------------- pre-split weights into 3 bf16 planes, frag-blocked kti-major ----------------
__global__ void k_splitW(const float* __restrict__ W, unsigned short* __restrict__ out, int K) {
  int e = blockIdx.x*256 + threadIdx.x;
  if (e >= DD*K) return;
  int j    = e & 7;
  int lane = (e >> 3) & 63;
  int nt   = (e >> 9) & 7;
  int s    = (e >> 12) & 1;
  int kti  = e >> 13;
  int n = nt*32 + (lane & 31);
  int k = kti*32 + s*16 + ((lane >> 5) << 3) + j;
  float x = W[(size_t)k*DD + n];
  unsigned short h1 = f2bf(x);  float r1 = x - bf2f(h1);
  unsigned short h2 = f2bf(r1); float r2 = r1 - bf2f(h2);
  unsigned short h3 = f2bf(r2);
  out[e] = h1; out[DD*K + e] = h2; out[2*DD*K + e] = h3;
}

// ---------------- mask + norm: wave per row; 4 x ballot -> 256-bit row mask ----------------
__global__ void k_maskrow(const float* __restrict__ adj, float* __restrict__ norm0,
                          unsigned long long* __restrict__ mask) {
  int row = blockIdx.x*4 + (threadIdx.x >> 6);
  int lane = threadIdx.x & 63;
  const float* ar = adj + (size_t)row*NN;
  float f0 = ar[lane], f1 = ar[64 + lane], f2 = ar[128 + lane], f3 = ar[192 + lane];
  unsigned long long m0 = __ballot(f0 > 0.5f);
  unsigned long long m1 = __ballot(f1 > 0.5f);
  unsigned long long m2 = __ballot(f2 > 0.5f);
  unsigned long long m3 = __ballot(f3 > 0.5f);
  if (lane < 4) {
    unsigned long long mm = lane == 0 ? m0 : lane == 1 ? m1 : lane == 2 ? m2 : m3;
    mask[(size_t)row*4 + lane] = mm;
  }
  if (lane == 0) {
    int cnt = __popcll(m0) + __popcll(m1) + __popcll(m2) + __popcll(m3);
    norm0[row] = rsqrtf(fmaxf((float)cnt, 1.0f));
  }
}

// ---------------- fused xsplit + spmm: T0 = A @ (X*norm), A from bitmask ----------------
// LDS: quarter-K (64 rows) of 3-way-split Xn, layout [sp][c(128)][k(64)] stride 68.
constexpr int QS = 68;                 // LDS k-stride (elems); 4-elem aligned
__global__ __launch_bounds__(256, 2) void k_spmm_f(
    const float* __restrict__ feat, const unsigned long long* __restrict__ mask,
    const float* __restrict__ norm0, float* __restrict__ T0) {
  __shared__ unsigned short ls[3*128*QS];   // 52224 B
  __shared__ float snorm[NN];

  int g = blockIdx.x;
  int t = threadIdx.x;
  int lane = t & 63, wave = t >> 6;
  int lm = lane & 31, lh = lane >> 5;

  const float* Xg = feat + (size_t)g*NN*FF;

  snorm[t] = norm0[g*NN + t];

  // per-lane adjacency row masks: rows wave*64 + mt*32 + lm
  unsigned long long mrow[2][4];
  #pragma unroll
  for (int mt = 0; mt < 2; ++mt) {
    const unsigned long long* mp = mask + ((size_t)g*NN + wave*64 + mt*32 + lm)*4;
    #pragma unroll
    for (int w = 0; w < 4; ++w) mrow[mt][w] = mp[w];
  }

  f32x16 acc[2][4];
  #pragma unroll
  for (int i = 0; i < 2; ++i)
    #pragma unroll
    for (int j = 0; j < 4; ++j) acc[i][j] = (f32x16)0.0f;

  __syncthreads();   // snorm ready

  for (int kq = 0; kq < 4; ++kq) {       // quarters of K=256
    // ---- stage quarter: 64 k-rows x 128 cols, 3-way split, k-contiguous in LDS ----
    #pragma unroll
    for (int i = 0; i < 8; ++i) {
      int g2 = t + i*256;                // 0..2047
      int c  = g2 & 127;
      int mg = g2 >> 7;                  // 0..15 (4-row groups)
      int m0 = kq*64 + mg*4;
      unsigned long long p1 = 0, p2 = 0, p3 = 0;
      #pragma unroll
      for (int jj = 0; jj < 4; ++jj) {
        float x = Xg[(size_t)(m0 + jj)*FF + c] * snorm[m0 + jj];
        unsigned short h1 = f2bf(x);  float r1 = x - bf2f(h1);
        unsigned short h2 = f2bf(r1); float r2 = r1 - bf2f(h2);
        unsigned short h3 = f2bf(r2);
        p1 |= (unsigned long long)h1 << (16*jj);
        p2 |= (unsigned long long)h2 << (16*jj);
        p3 |= (unsigned long long)h3 << (16*jj);
      }
      int base = c*QS + mg*4;
      *reinterpret_cast<unsigned long long*>(&ls[base])            = p1;
      *reinterpret_cast<unsigned long long*>(&ls[128*QS + base])   = p2;
      *reinterpret_cast<unsigned long long*>(&ls[2*128*QS + base]) = p3;
    }
    __syncthreads();

    // ---- MFMA: 2 kt-iters of 32 within the quarter ----
    #pragma unroll
    for (int ktq = 0; ktq < 2; ++ktq) {
      // A-frags from mask bits: k = kq*64 + ktq*32 + s*16 + lh*8 + j
      Frag8 afr[2][2];
      #pragma unroll
      for (int mt = 0; mt < 2; ++mt)
        #pragma unroll
        for (int s = 0; s < 2; ++s) {
          int shift = ktq*32 + s*16 + lh*8;
          unsigned byte = (unsigned)(mrow[mt][kq] >> shift) & 0xFFu;
          #pragma unroll
          for (int j = 0; j < 8; ++j)
            afr[mt][s].us[j] = ((byte >> j) & 1u) ? (unsigned short)0x3F80 : (unsigned short)0;
        }
      #pragma unroll
      for (int s = 0; s < 2; ++s)
        #pragma unroll
        for (int nt = 0; nt < 4; ++nt) {
          int kk = ktq*32 + s*16 + lh*8;
          int base = (nt*32 + lm)*QS + kk;
          Frag8 b0_, b1_, b2_;
          b0_.v = *reinterpret_cast<const bf16x8*>(&ls[base]);
          b1_.v = *reinterpret_cast<const bf16x8*>(&ls[128*QS + base]);
          b2_.v = *reinterpret_cast<const bf16x8*>(&ls[2*128*QS + base]);
          #pragma unroll
          for (int mt = 0; mt < 2; ++mt) {
            acc[mt][nt] = __builtin_amdgcn_mfma_f32_32x32x16_bf16(afr[mt][s].v, b0_.v, acc[mt][nt], 0,0,0);
            acc[mt][nt] = __builtin_amdgcn_mfma_f32_32x32x16_bf16(afr[mt][s].v, b1_.v, acc[mt][nt], 0,0,0);
            acc[mt][nt] = __builtin_amdgcn_mfma_f32_32x32x16_bf16(afr[mt][s].v, b2_.v, acc[mt][nt], 0,0,0);
          }
        }
    }
    __syncthreads();
  }

  // epilogue: C/D layout col=lane&31, row=(reg&3)+8*(reg>>2)+4*(lane>>5)
  #pragma unroll
  for (int mt = 0; mt < 2; ++mt)
    #pragma unroll
    for (int nt = 0; nt < 4; ++nt)
      #pragma unroll
      for (int r = 0; r < 16; ++r) {
        int row = wave*64 + mt*32 + (r & 3) + 8*(r >> 2) + 4*lh;
        int col = nt*32 + lm;
        T0[((size_t)g*NN + row)*FF + col] = acc[mt][nt][r];
      }
}

// ---------------- layer0 GEMM: 4-wave blocks, B staged in LDS (shared by waves) ----------------
__global__ __launch_bounds__(256, 2) void k_gemm0(
    const float* __restrict__ Tmat, const unsigned short* __restrict__ Wk,
    const float* __restrict__ normv, const float* __restrict__ bias,
    const float* __restrict__ Ws, float* __restrict__ hs) {
  __shared__ unsigned short bsh[3*8192];   // 48 KB: one k-tile of all 3 planes
  int t = threadIdx.x;
  int lane = t & 63, wave = t >> 6;
  int lm = lane & 31, lh = lane >> 5;
  int rowbase = blockIdx.x*128 + wave*32;

  f32x16 acc[8];
  #pragma unroll
  for (int nt = 0; nt < 8; ++nt) acc[nt] = (f32x16)0.0f;

  for (int kti = 0; kti < 4; ++kti) {
    int kt = kti*32;
    float4 af[2][2];
    #pragma unroll
    for (int s = 0; s < 2; ++s) {
      const float* ap = Tmat + (size_t)(rowbase + lm)*FF + kt + s*16 + lh*8;
      af[s][0] = *reinterpret_cast<const float4*>(ap);
      af[s][1] = *reinterpret_cast<const float4*>(ap + 4);
    }
    __syncthreads();
    #pragma unroll
    for (int sp = 0; sp < 3; ++sp)
      #pragma unroll
      for (int r = 0; r < 4; ++r) {
        const uint4* src = reinterpret_cast<const uint4*>(
            Wk + (size_t)sp*DD*FF + (size_t)kti*8192 + r*2048 + t*8);
        *reinterpret_cast<uint4*>(bsh + sp*8192 + r*2048 + t*8) = *src;
      }
    __syncthreads();
    Frag8 afr[2][3];
    #pragma unroll
    for (int s = 0; s < 2; ++s) {
      const float* fv = &af[s][0].x;
      #pragma unroll
      for (int j = 0; j < 8; ++j) {
        float x = fv[j];
        unsigned short h1 = f2bf(x);  float r1 = x - bf2f(h1);
        unsigned short h2 = f2bf(r1); float r2 = r1 - bf2f(h2);
        afr[s][0].us[j] = h1; afr[s][1].us[j] = h2; afr[s][2].us[j] = f2bf(r2);
      }
    }
    #pragma unroll
    for (int s = 0; s < 2; ++s)
      #pragma unroll
      for (int nt = 0; nt < 8; ++nt) {
        const unsigned short* bp = bsh + ((s*8 + nt)*64 + lane)*8;
        Frag8 b0_, b1_, b2_;
        b0_.v = *reinterpret_cast<const bf16x8*>(bp);
        b1_.v = *reinterpret_cast<const bf16x8*>(bp + 8192);
        b2_.v = *reinterpret_cast<const bf16x8*>(bp + 16384);
        acc[nt] = __builtin_amdgcn_mfma_f32_32x32x16_bf16(afr[s][0].v, b0_.v, acc[nt], 0,0,0);
        acc[nt] = __builtin_amdgcn_mfma_f32_32x32x16_bf16(afr[s][0].v, b1_.v, acc[nt], 0,0,0);
        acc[nt] = __builtin_amdgcn_mfma_f32_32x32x16_bf16(afr[s][1].v, b0_.v, acc[nt], 0,0,0);
        acc[nt] = __builtin_amdgcn_mfma_f32_32x32x16_bf16(afr[s][0].v, b2_.v, acc[nt], 0,0,0);
        acc[nt] = __builtin_amdgcn_mfma_f32_32x32x16_bf16(afr[s][2].v, b0_.v, acc[nt], 0,0,0);
        acc[nt] = __builtin_amdgcn_mfma_f32_32x32x16_bf16(afr[s][1].v, b1_.v, acc[nt], 0,0,0);
      }
  }

  float bcol[8], wcol[8];
  #pragma unroll
  for (int nt = 0; nt < 8; ++nt) { int col = nt*32 + lm; bcol[nt] = bias[col]; wcol[nt] = Ws[col]; }
  float hsum[16];
  #pragma unroll
  for (int r = 0; r < 16; ++r) {
    int row = rowbase + (r & 3) + 8*(r >> 2) + 4*lh;
    float nv = normv[row];
    float hp = 0.f;
    #pragma unroll
    for (int nt = 0; nt < 8; ++nt) hp += lrelu(nv*acc[nt][r] + bcol[nt])*wcol[nt];
    hsum[r] = hp;
  }
  #pragma unroll
  for (int off = 1; off <= 16; off <<= 1)
    #pragma unroll
    for (int r = 0; r < 16; ++r) hsum[r] += __shfl_xor(hsum[r], off);
  if (lm == 0)
    #pragma unroll
    for (int r = 0; r < 16; ++r) {
      int row = rowbase + (r & 3) + 8*(r >> 2) + 4*lh;
      hs[row] = normv[row]*hsum[r];
    }
}

// ---------------- MFMA GEMM (layers 1/2), LDS-free: one wave = 32 rows x 256 cols ----------------
template<int K, bool WRITE_X>
__global__ __launch_bounds__(64, 2) void k_gemm_mfma(
    const float* __restrict__ Tmat, const unsigned short* __restrict__ Wk,
    const float* __restrict__ normv, const float* __restrict__ bias,
    const float* __restrict__ Ws, float* __restrict__ xout, float* __restrict__ hs) {
  int lane = threadIdx.x;
  int lm = lane & 31, lh = lane >> 5;
  int rowbase = blockIdx.x * 32;

  f32x16 acc[8];
  #pragma unroll
  for (int nt = 0; nt < 8; ++nt) acc[nt] = (f32x16)0.0f;

  for (int kt = 0; kt < K; kt += 32) {
    float4 af[2][2];
    #pragma unroll
    for (int s = 0; s < 2; ++s) {
      const float* ap = Tmat + (size_t)(rowbase + lm)*K + kt + s*16 + lh*8;
      af[s][0] = *reinterpret_cast<const float4*>(ap);
      af[s][1] = *reinterpret_cast<const float4*>(ap + 4);
    }
    Frag8 afr[2][3];
    #pragma unroll
    for (int s = 0; s < 2; ++s) {
      const float* fv = &af[s][0].x;
      #pragma unroll
      for (int j = 0; j < 8; ++j) {
        float x = fv[j];
        unsigned short h1 = f2bf(x);  float r1 = x - bf2f(h1);
        unsigned short h2 = f2bf(r1); float r2 = r1 - bf2f(h2);
        afr[s][0].us[j] = h1; afr[s][1].us[j] = h2; afr[s][2].us[j] = f2bf(r2);
      }
    }
    #pragma unroll
    for (int s = 0; s < 2; ++s)
      #pragma unroll
      for (int nt = 0; nt < 8; ++nt) {
        size_t boff = ((((size_t)(kt >> 5)*2 + s)*8 + nt)*64 + lane)*8;
        Frag8 b0_, b1_, b2_;
        b0_.v = *reinterpret_cast<const bf16x8*>(Wk + boff);
        b1_.v = *reinterpret_cast<const bf16x8*>(Wk + (size_t)DD*K + boff);
        b2_.v = *reinterpret_cast<const bf16x8*>(Wk + (size_t)2*DD*K + boff);
        acc[nt] = __builtin_amdgcn_mfma_f32_32x32x16_bf16(afr[s][0].v, b0_.v, acc[nt], 0,0,0);
        acc[nt] = __builtin_amdgcn_mfma_f32_32x32x16_bf16(afr[s][0].v, b1_.v, acc[nt], 0,0,0);
        acc[nt] = __builtin_amdgcn_mfma_f32_32x32x16_bf16(afr[s][1].v, b0_.v, acc[nt], 0,0,0);
        acc[nt] = __builtin_amdgcn_mfma_f32_32x32x16_bf16(afr[s][0].v, b2_.v, acc[nt], 0,0,0);
        acc[nt] = __builtin_amdgcn_mfma_f32_32x32x16_bf16(afr[s][2].v, b0_.v, acc[nt], 0,0,0);
        acc[nt] = __builtin_amdgcn_mfma_f32_32x32x16_bf16(afr[s][1].v, b1_.v, acc[nt], 0,0,0);
      }
  }

  float bcol[8], wcol[8];
  #pragma unroll
  for (int nt = 0; nt < 8; ++nt) { int col = nt*32 + lm; bcol[nt] = bias[col]; wcol[nt] = Ws[col]; }
  float hsum[16];
  #pragma unroll
  for (int r = 0; r < 16; ++r) {
    int row = rowbase + (r & 3) + 8*(r >> 2) + 4*lh;
    float nv = normv[row];
    float hp = 0.f;
    #pragma unroll
    for (int nt = 0; nt < 8; ++nt) {
      float val = lrelu(nv*acc[nt][r] + bcol[nt]);
      if (WRITE_X) xout[(size_t)row*DD + nt*32 + lm] = val;
      hp += val*wcol[nt];
    }
    hsum[r] = hp;
  }
  #pragma unroll
  for (int off = 1; off <= 16; off <<= 1)
    #pragma unroll
    for (int r = 0; r < 16; ++r) hsum[r] += __shfl_xor(hsum[r], off);
  if (lm == 0)
    #pragma unroll
    for (int r = 0; r < 16; ++r) {
      int row = rowbase + (r & 3) + 8*(r >> 2) + 4*lh;
      hs[row] = normv[row]*hsum[r];
    }
}

// ---------------- layer0: score via bitmask + fused top-k ----------------
__global__ void k_score_topk0(const unsigned long long* __restrict__ mask,
                              const float* __restrict__ hs, const float* __restrict__ norm0,
                              const float* __restrict__ bs,
                              int* __restrict__ idx_out, float* __restrict__ tv_out) {
  __shared__ float sh[NN];
  __shared__ float ssc[NN];
  int g = blockIdx.x, t = threadIdx.x;
  sh[t] = hs[g*NN + t];
  __syncthreads();
  const unsigned long long* mr = mask + ((size_t)g*NN + t)*4;
  float s = 0.f;
  #pragma unroll
  for (int w = 0; w < 4; ++w) {
    unsigned long long m = mr[w];
    const float* base = sh + w*64;
    while (m) {
      int c = __builtin_ctzll(m);
      s += base[c];
      m &= m - 1;
    }
  }
  ssc[t] = norm0[g*NN + t]*s + bs[0];
  __syncthreads();
  if (t < 64) {
    float sv[4]; int si[4];
    #pragma unroll
    for (int e = 0; e < 4; ++e) { sv[e] = ssc[e*64 + t]; si[e] = e*64 + t; }
    for (int kk = 0; kk < KS0; ++kk) {
      float bs_ = -INFINITY; int bi = 1 << 30;
      #pragma unroll
      for (int e = 0; e < 4; ++e)
        if (sv[e] > bs_ || (sv[e] == bs_ && si[e] < bi)) { bs_ = sv[e]; bi = si[e]; }
      for (int off = 32; off; off >>= 1) {
        float os = __shfl_xor(bs_, off);
        int oi = __shfl_xor(bi, off);
        if (os > bs_ || (os == bs_ && oi < bi)) { bs_ = os; bi = oi; }
      }
      if (t == 0) { idx_out[g*KS0 + kk] = bi; tv_out[g*KS0 + kk] = tanhf(bs_); }
      #pragma unroll
      for (int e = 0; e < 4; ++e) if (si[e] == bi) sv[e] = -INFINITY;
    }
  }
}

// ---------------- layer0 selection: recompute x1 rows for top-32, gate, readout, a1 from mask ----------------
__global__ void k_sel0(const float* __restrict__ T0, const float* __restrict__ W0,
                       const float* __restrict__ norm0, const float* __restrict__ b0,
                       const int* __restrict__ idx, const float* __restrict__ tv,
                       const unsigned long long* __restrict__ mask, float* __restrict__ x_sel,
                       float* __restrict__ a1, float* __restrict__ merged) {
  __shared__ float sT[KS0*FF];     // 16 KB
  __shared__ int sidx[KS0]; __shared__ float stv[KS0]; __shared__ float snv[KS0];
  int g = blockIdx.x, t = threadIdx.x;
  if (t < KS0) { sidx[t] = idx[g*KS0 + t]; stv[t] = tv[g*KS0 + t]; }
  __syncthreads();
  if (t < KS0) snv[t] = norm0[g*NN + sidx[t]];
  #pragma unroll
  for (int i = 0; i < 16; ++i) {
    int e = t + i*256, r = e >> 7, c = e & 127;
    sT[e] = T0[((size_t)g*NN + sidx[r])*FF + c];
  }
  __syncthreads();
  float sum[KS0];
  #pragma unroll
  for (int j = 0; j < KS0; ++j) sum[j] = 0.f;
  for (int k = 0; k < FF; k += 4) {
    float4 w;
    w.x = W0[(size_t)(k+0)*DD + t]; w.y = W0[(size_t)(k+1)*DD + t];
    w.z = W0[(size_t)(k+2)*DD + t]; w.w = W0[(size_t)(k+3)*DD + t];
    #pragma unroll
    for (int j = 0; j < KS0; ++j) {
      float4 tv4 = *reinterpret_cast<const float4*>(&sT[j*FF + k]);
      sum[j] += tv4.x*w.x + tv4.y*w.y + tv4.z*w.z + tv4.w*w.w;
    }
  }
  float b = b0[t];
  float s = 0.f, mx = -INFINITY;
  #pragma unroll
  for (int j = 0; j < KS0; ++j) {
    float val = lrelu(snv[j]*sum[j] + b) * stv[j];
    x_sel[((size_t)g*KS0 + j)*DD + t] = val;
    s += val; mx = fmaxf(mx, val);
  }
  merged[(size_t)g*1536 + t] = s;
  merged[(size_t)g*1536 + 256 + t] = mx;
  for (int e = t; e < KS0*KS0; e += 256) {
    int r = e >> 5, c = e & 31;
    int nr = sidx[r], nc = sidx[c];
    unsigned long long m = mask[((size_t)g*NN + nr)*4 + (nc >> 6)];
    a1[(size_t)g*KS0*KS0 + e] = (float)((m >> (nc & 63)) & 1ull);
  }
}

// ---------------- fused pool (layers 1/2): score + top-k + gather + readout ----------------
template<int n, int k, bool LAST>
__global__ void k_pool(const float* __restrict__ x, const float* __restrict__ a,
                       const float* __restrict__ hs, const float* __restrict__ normv,
                       const float* __restrict__ bs, float* __restrict__ x_sel,
                       float* __restrict__ a_out, float* __restrict__ merged, int moff) {
  __shared__ float sa[n*n];
  __shared__ float shs[n];
  __shared__ float ssc[n];
  __shared__ int sidx[k]; __shared__ float stv[k];
  int g = blockIdx.x, t = threadIdx.x;
  for (int e = t; e < n*n; e += 256) sa[e] = a[(size_t)g*n*n + e];
  if (t < n) shs[t] = hs[g*n + t];
  __syncthreads();
  if (t < n) {
    float s = 0.f;
    #pragma unroll
    for (int m = 0; m < n; ++m) s += sa[t*n + m]*shs[m];
    ssc[t] = normv[g*n + t]*s + bs[0];
  }
  __syncthreads();
  if (t < 64) {
    float sc = (t < n) ? ssc[t] : -INFINITY;
    int si = (t < n) ? t : (1 << 30);
    for (int kk = 0; kk < k; ++kk) {
      float bs_ = sc; int bi = si;
      for (int off = 32; off; off >>= 1) {
        float os = __shfl_xor(bs_, off);
        int oi = __shfl_xor(bi, off);
        if (os > bs_ || (os == bs_ && oi < bi)) { bs_ = os; bi = oi; }
      }
      if (t == 0) { sidx[kk] = bi; stv[kk] = tanhf(bs_); }
      if (si == bi) sc = -INFINITY;
    }
  }
  __syncthreads();
  float sum = 0.f, mx = -INFINITY;
  #pragma unroll
  for (int j = 0; j < k; ++j) {
    float v = x[((size_t)g*n + sidx[j])*DD + t] * stv[j];
    if (!LAST) x_sel[((size_t)g*k + j)*DD + t] = v;
    sum += v; mx = fmaxf(mx, v);
  }
  merged[(size_t)g*1536 + moff + t] = sum;
  merged[(size_t)g*1536 + moff + 256 + t] = mx;
  if (!LAST && t < k*k) {
    int r = t / k, c = t - r*k;
    a_out[(size_t)g*k*k + t] = sa[sidx[r]*n + sidx[c]];
  }
}

// ---------------- dense small spmm: norm from a, T = a @ (x*norm) ----------------
template<int n>
__global__ void k_spmm_dense(const float* __restrict__ a, const float* __restrict__ x,
                             float* __restrict__ normv, float* __restrict__ T) {
  __shared__ float sa[n*n];
  __shared__ float snorm[n];
  __shared__ float sx[n*DD];
  int g = blockIdx.x; int t = threadIdx.x;
  for (int e = t; e < n*n; e += 256) sa[e] = a[(size_t)g*n*n + e];
  __syncthreads();
  if (t < n) {
    float dg = 0.f;
    for (int m = 0; m < n; ++m) dg += sa[t*n + m];
    float nv = rsqrtf(fmaxf(dg, 1.f));
    snorm[t] = nv; normv[g*n + t] = nv;
  }
  __syncthreads();
  for (int e = t; e < n*DD; e += 256) sx[e] = x[(size_t)g*n*DD + e] * snorm[e >> 8];
  __syncthreads();
  float acc[n];
  #pragma unroll
  for (int r = 0; r < n; ++r) acc[r] = 0.f;
  for (int m = 0; m < n; ++m) {
    float xv = sx[m*DD + t];
    #pragma unroll
    for (int r = 0; r < n; ++r) acc[r] += sa[r*n + m]*xv;
  }
  for (int r = 0; r < n; ++r) T[((size_t)g*n + r)*DD + t] = acc[r];
}

// ---------------- final MLP: 4 graphs per block for Wd1 reuse ----------------
__global__ void k_mlp(const float* __restrict__ merged, const float* __restrict__ Wd1,
                      const float* __restrict__ bd1, const float* __restrict__ Wd2,
                      const float* __restrict__ bd2, float* __restrict__ out) {
  __shared__ float sm[4*1536];
  __shared__ float sh[4][128];
  int g0 = blockIdx.x*4; int t = threadIdx.x;     // 128 threads
  for (int i = t; i < 4*1536; i += 128) sm[i] = merged[(size_t)g0*1536 + i];
  __syncthreads();
  float a0 = 0.f, a1 = 0.f, a2 = 0.f, a3 = 0.f;
  for (int kk = 0; kk < 1536; ++kk) {
    float w = Wd1[(size_t)kk*128 + t];
    a0 += sm[kk]*w; a1 += sm[1536 + kk]*w; a2 += sm[3072 + kk]*w; a3 += sm[4608 + kk]*w;
  }
  float b = bd1[t];
  sh[0][t] = lrelu(a0 + b); sh[1][t] = lrelu(a1 + b);
  sh[2][t] = lrelu(a2 + b); sh[3][t] = lrelu(a3 + b);
  __syncthreads();
  if (t < 8) {
    int gi = t >> 1, c = t & 1;
    float o = 0.f;
    for (int kk = 0; kk < 128; ++kk) o += sh[gi][kk]*Wd2[kk*2 + c];
    out[(size_t)(g0 + gi)*2 + c] = 1.f/(1.f + expf(-(o + bd2[c])));
  }
}

extern "C" void kernel_launch(void* const* d_in, const int* in_sizes, int n_in,
                              void* d_out, int out_size, void* d_ws, size_t ws_size,
                              hipStream_t stream) {
  const float* feat = (const float*)d_in[0];
  const float* adj  = (const float*)d_in[1];
  const float* W0 = (const float*)d_in[2];  const float* b0  = (const float*)d_in[3];
  const float* Ws0= (const float*)d_in[4];  const float* bs0 = (const float*)d_in[5];
  const float* W1 = (const float*)d_in[6];  const float* b1  = (const float*)d_in[7];
  const float* Ws1= (const float*)d_in[8];  const float* bs1 = (const float*)d_in[9];
  const float* W2 = (const float*)d_in[10]; const float* b2  = (const float*)d_in[11];
  const float* Ws2= (const float*)d_in[12]; const float* bs2 = (const float*)d_in[13];
  const float* Wd1= (const float*)d_in[14]; const float* bd1 = (const float*)d_in[15];
  const float* Wd2= (const float*)d_in[16]; const float* bd2 = (const float*)d_in[17];
  float* out = (float*)d_out;

  char* ws = (char*)d_ws;
  size_t off = 0;
  auto alloc = [&](size_t bytes) -> char* {
    char* p = ws + off; off += (bytes + 255) & ~(size_t)255; return p;
  };
  float* norm0 = (float*)alloc((size_t)GG*NN*4);
  unsigned long long* mask0 = (unsigned long long*)alloc((size_t)GG*NN*4*8);
  float* hs0   = (float*)alloc((size_t)GG*NN*4);
  int*   idx0  = (int*)  alloc((size_t)GG*KS0*4);
  float* tv0   = (float*)alloc((size_t)GG*KS0*4);
  float* norm1 = (float*)alloc((size_t)GG*KS0*4);
  float* hs1   = (float*)alloc((size_t)GG*KS0*4);
  float* norm2 = (float*)alloc((size_t)GG*KS1*4);
  float* hs2   = (float*)alloc((size_t)GG*KS1*4);
  float* merged= (float*)alloc((size_t)GG*1536*4);
  unsigned short* W0s = (unsigned short*)alloc((size_t)3*FF*DD*2);
  unsigned short* W1s = (unsigned short*)alloc((size_t)3*DD*DD*2);
  unsigned short* W2s = (unsigned short*)alloc((size_t)3*DD*DD*2);
  char* regA = alloc((size_t)GG*NN*FF*4);        // 128 MB: T0, later T1
  char* regB = alloc((size_t)GG*160*DD*4);       // layer1+ buffers

  float* T0 = (float*)regA;
  float* T1 = (float*)regA;                 // reuse after k_sel0 consumed T0
  float* x_sel1 = (float*)regB;                                      // 32 MB
  float* a1     = (float*)(regB + (size_t)GG*KS0*DD*4);              //  4 MB
  float* x2     = (float*)((char*)a1     + (size_t)GG*KS0*KS0*4);    // 32 MB
  float* x_sel2 = (float*)((char*)x2     + (size_t)GG*KS0*DD*4);     // 16 MB
  float* a2     = (float*)((char*)x_sel2 + (size_t)GG*KS1*DD*4);     //  1 MB
  float* T2     = (float*)((char*)a2     + (size_t)GG*KS1*KS1*4);    // 16 MB
  float* x3     = (float*)((char*)T2     + (size_t)GG*KS1*DD*4);     // 16 MB

  // ---- weight pre-split (frag-blocked kti-major layout) ----
  k_splitW<<<(FF*DD + 255)/256, 256, 0, stream>>>(W0, W0s, FF);
  k_splitW<<<(DD*DD + 255)/256, 256, 0, stream>>>(W1, W1s, DD);
  k_splitW<<<(DD*DD + 255)/256, 256, 0, stream>>>(W2, W2s, DD);

  // ---- layer 0 ----
  k_maskrow<<<GG*NN/4, 256, 0, stream>>>(adj, norm0, mask0);
  k_spmm_f<<<GG, 256, 0, stream>>>(feat, mask0, norm0, T0);
  k_gemm0<<<GG*NN/128, 256, 0, stream>>>(T0, W0s, norm0, b0, Ws0, hs0);
  k_score_topk0<<<GG, 256, 0, stream>>>(mask0, hs0, norm0, bs0, idx0, tv0);
  k_sel0<<<GG, 256, 0, stream>>>(T0, W0, norm0, b0, idx0, tv0, mask0, x_sel1, a1, merged);

  // ---- layer 1 ----
  k_spmm_dense<KS0><<<GG, 256, 0, stream>>>(a1, x_sel1, norm1, T1);
  k_gemm_mfma<DD, true><<<GG*KS0/32, 64, 0, stream>>>(T1, W1s, norm1, b1, Ws1, x2, hs1);
  k_pool<KS0, KS1, false><<<GG, 256, 0, stream>>>(x2, a1, hs1, norm1, bs1, x_sel2, a2, merged, 512);

  // ---- layer 2 ----
  k_spmm_dense<KS1><<<GG, 256, 0, stream>>>(a2, x_sel2, norm2, T2);
  k_gemm_mfma<DD, true><<<GG*KS1/32, 64, 0, stream>>>(T2, W2s, norm2, b2, Ws2, x3, hs2);
  k_pool<KS1, KS2, true><<<GG, 256, 0, stream>>>(x3, a2, hs2, norm2, bs2, nullptr, nullptr, merged, 1024);

  // ---- MLP head ----
  k_mlp<<<GG/4, 128, 0, stream>>>(merged, Wd1, bd1, Wd2, bd2, out);

  (void)in_sizes; (void)n_in; (void)out_size; (void)ws_size;
}